// Round 1
// baseline (1121.689 us; speedup 1.0000x reference)
//
#include <hip/hip_runtime.h>
#include <cstdint>
#include <cstddef>

typedef unsigned short u16;
typedef unsigned int u32;
typedef __attribute__((ext_vector_type(4))) u16 u16x4;
typedef __attribute__((ext_vector_type(8))) u16 u16x8;
typedef __attribute__((ext_vector_type(4))) float f32x4;
typedef __attribute__((ext_vector_type(8))) __bf16 bf16x8;

#define DEV static __device__ __forceinline__

DEV u16 f2bf(float f) {
  u32 u = __builtin_bit_cast(u32, f);
  u32 r = (u + 0x7FFFu + ((u >> 16) & 1u)) >> 16;
  return (u16)r;
}
DEV float bf2f(u16 s) { return __builtin_bit_cast(float, (u32)s << 16); }

constexpr int B_ = 2, L_ = 4096, H_ = 8;
constexpr int BL = B_ * L_;   // 8192 tokens
constexpr int NC = L_ / 32;   // 128 chunks per sequence

// ---------------------------------------------------------------------------
// f32 -> bf16 convert (hidden)
// ---------------------------------------------------------------------------
__global__ __launch_bounds__(256) void k_f32_to_bf16(const float* __restrict__ src,
                                                     u16* __restrict__ dst, int n4) {
  int i = blockIdx.x * 256 + threadIdx.x;
  if (i < n4) {
    f32x4 v = *(const f32x4*)(src + (size_t)i * 4);
    u16x4 o;
#pragma unroll
    for (int j = 0; j < 4; ++j) o[j] = f2bf(v[j]);
    *(u16x4*)(dst + (size_t)i * 4) = o;
  }
}

// ---------------------------------------------------------------------------
// transpose 1024x1024 f32 weights -> bf16 [n][k]
// ---------------------------------------------------------------------------
__global__ __launch_bounds__(256) void k_transpose_w(const float* __restrict__ s0, const float* __restrict__ s1,
                                                     const float* __restrict__ s2, const float* __restrict__ s3,
                                                     u16* __restrict__ d0, u16* __restrict__ d1,
                                                     u16* __restrict__ d2, u16* __restrict__ d3) {
  const float* src = blockIdx.z == 0 ? s0 : blockIdx.z == 1 ? s1 : blockIdx.z == 2 ? s2 : s3;
  u16* dst = blockIdx.z == 0 ? d0 : blockIdx.z == 1 ? d1 : blockIdx.z == 2 ? d2 : d3;
  __shared__ float tile[32][33];
  int k0 = blockIdx.y * 32, n0 = blockIdx.x * 32;
  int ty = threadIdx.x >> 5, tx = threadIdx.x & 31;
#pragma unroll
  for (int i = 0; i < 4; ++i)
    tile[ty + 8 * i][tx] = src[(size_t)(k0 + ty + 8 * i) * 1024 + n0 + tx];
  __syncthreads();
#pragma unroll
  for (int i = 0; i < 4; ++i) {
    int nl = ty + 8 * i;
    dst[(size_t)(n0 + nl) * 1024 + k0 + tx] = f2bf(tile[tx][nl]);
  }
}

// ---------------------------------------------------------------------------
// bf16 GEMM: C[M,N] = A[M,K] * Bt[N,K]^T ; 128x128 tile, 4 waves, 16x16x32 MFMA
// ---------------------------------------------------------------------------
template<bool STORE_BF16>
__global__ __launch_bounds__(256) void gemm_bt(const u16* __restrict__ A, const u16* __restrict__ Bt,
                                               void* __restrict__ Cout, int M, int N, int K) {
  __shared__ u16 Ash[128 * 32];
  __shared__ u16 Bsh[128 * 32];
  const int tid = threadIdx.x;
  const int lane = tid & 63, w = tid >> 6;
  const int wr = w >> 1, wc = w & 1;
  const int g = lane >> 4, li = lane & 15;
  const int mblk = blockIdx.y * 128, nblk = blockIdx.x * 128;
  const int srow = tid >> 2, sslot = tid & 3;

  f32x4 acc[4][4];
#pragma unroll
  for (int m = 0; m < 4; ++m)
#pragma unroll
    for (int n = 0; n < 4; ++n) acc[m][n] = (f32x4){0.f, 0.f, 0.f, 0.f};

  for (int kt = 0; kt < K; kt += 32) {
    __syncthreads();
#pragma unroll
    for (int half = 0; half < 2; ++half) {
      int row = srow + half * 64;
      int gk = kt + ((sslot ^ (row & 3)) << 3);  // XOR-swizzled source k-group
      u16x8 av = *(const u16x8*)(A + (size_t)(mblk + row) * K + gk);
      *(u16x8*)&Ash[row * 32 + sslot * 8] = av;
      u16x8 bv = *(const u16x8*)(Bt + (size_t)(nblk + row) * K + gk);
      *(u16x8*)&Bsh[row * 32 + sslot * 8] = bv;
    }
    __syncthreads();
    bf16x8 af[4], bfr[4];
#pragma unroll
    for (int m = 0; m < 4; ++m) {
      int row = wr * 64 + m * 16 + li;
      af[m] = *(const bf16x8*)&Ash[row * 32 + ((g ^ (li & 3)) << 3)];
    }
#pragma unroll
    for (int n = 0; n < 4; ++n) {
      int row = wc * 64 + n * 16 + li;
      bfr[n] = *(const bf16x8*)&Bsh[row * 32 + ((g ^ (li & 3)) << 3)];
    }
#pragma unroll
    for (int m = 0; m < 4; ++m)
#pragma unroll
      for (int n = 0; n < 4; ++n)
        acc[m][n] = __builtin_amdgcn_mfma_f32_16x16x32_bf16(af[m], bfr[n], acc[m][n], 0, 0, 0);
  }
#pragma unroll
  for (int m = 0; m < 4; ++m)
#pragma unroll
    for (int n = 0; n < 4; ++n)
#pragma unroll
      for (int r = 0; r < 4; ++r) {
        int grow = mblk + wr * 64 + m * 16 + g * 4 + r;
        int gcol = nblk + wc * 64 + n * 16 + li;
        if constexpr (STORE_BF16)
          ((u16*)Cout)[(size_t)grow * N + gcol] = f2bf(acc[m][n][r]);
        else
          ((float*)Cout)[(size_t)grow * N + gcol] = acc[m][n][r];
      }
}

// ---------------------------------------------------------------------------
// beta = sigmoid(hidden @ b_w) ; g = sigmoid(hidden @ mix_w + mix_b + mix_bias)
// ---------------------------------------------------------------------------
__global__ __launch_bounds__(256) void k_beta_g(const float* __restrict__ hidden, const float* __restrict__ b_w,
                                                const float* __restrict__ mix_w, const float* __restrict__ mix_b,
                                                const float* __restrict__ mix_bias,
                                                float* __restrict__ beta, float* __restrict__ g) {
  int idx = blockIdx.x * 256 + threadIdx.x;  // 0..65535 : (token, head)
  int t = idx >> 3, h = idx & 7;
  const f32x4* hrow = (const f32x4*)(hidden + (size_t)t * 1024);
  float sb = 0.f, sg = 0.f;
  for (int d4 = 0; d4 < 256; ++d4) {
    f32x4 hv = hrow[d4];
    int d = d4 * 4;
#pragma unroll
    for (int j = 0; j < 4; ++j) {
      sb += hv[j] * b_w[(d + j) * 8 + h];
      sg += hv[j] * mix_w[(d + j) * 8 + h];
    }
  }
  beta[idx] = 1.f / (1.f + expf(-sb));
  float gz = sg + mix_b[h] + mix_bias[h];
  g[idx] = 1.f / (1.f + expf(-gz));
}

// ---------------------------------------------------------------------------
// causal depthwise conv(K=4) + SiLU + per-head l2norm(q,k) + beta scaling
// one block per token; 256 threads x 4 channels
// ---------------------------------------------------------------------------
__global__ __launch_bounds__(256) void k_conv(const u16* __restrict__ qraw, const u16* __restrict__ kraw,
                                              const u16* __restrict__ vraw,
                                              const float* __restrict__ cqw, const float* __restrict__ ckw,
                                              const float* __restrict__ cvw, const float* __restrict__ beta,
                                              u16* __restrict__ qn, u16* __restrict__ kn, u16* __restrict__ kb,
                                              u16* __restrict__ vb, u16* __restrict__ vtok) {
  const int t = blockIdx.x;
  const int l = t & (L_ - 1);
  const int b = t >> 12;
  const int tid = threadIdx.x;
  const int c = tid * 4;
  const int h = c >> 7, dk = c & 127;
  float aq[4] = {0, 0, 0, 0}, ak[4] = {0, 0, 0, 0}, av[4] = {0, 0, 0, 0};
#pragma unroll
  for (int i = 0; i < 4; ++i) {
    int lr = l - 3 + i;
    if (lr < 0) continue;
    size_t off = (size_t)(t - 3 + i) * 1024 + c;
    u16x4 xq = *(const u16x4*)(qraw + off);
    u16x4 xk = *(const u16x4*)(kraw + off);
    u16x4 xv = *(const u16x4*)(vraw + off);
#pragma unroll
    for (int j = 0; j < 4; ++j) {
      aq[j] += bf2f(xq[j]) * cqw[(c + j) * 4 + i];
      ak[j] += bf2f(xk[j]) * ckw[(c + j) * 4 + i];
      av[j] += bf2f(xv[j]) * cvw[(c + j) * 4 + i];
    }
  }
#pragma unroll
  for (int j = 0; j < 4; ++j) {
    aq[j] = aq[j] / (1.f + expf(-aq[j]));
    ak[j] = ak[j] / (1.f + expf(-ak[j]));
    av[j] = av[j] / (1.f + expf(-av[j]));
  }
  float sq = aq[0] * aq[0] + aq[1] * aq[1] + aq[2] * aq[2] + aq[3] * aq[3];
  float sk = ak[0] * ak[0] + ak[1] * ak[1] + ak[2] * ak[2] + ak[3] * ak[3];
#pragma unroll
  for (int m = 1; m <= 16; m <<= 1) {
    sq += __shfl_xor(sq, m);
    sk += __shfl_xor(sk, m);
  }
  float rq = rsqrtf(sq + 1e-12f), rk = rsqrtf(sk + 1e-12f);
  float bv = beta[t * 8 + h];
  size_t hoff = ((size_t)(b * 8 + h) * L_ + l) * 128 + dk;
  u16x4 oq, ok, okb, ovb, ovt;
#pragma unroll
  for (int j = 0; j < 4; ++j) {
    float kq = aq[j] * rq;
    float kk = ak[j] * rk;
    oq[j] = f2bf(kq);
    ok[j] = f2bf(kk);
    okb[j] = f2bf(kk * bv);
    ovb[j] = f2bf(av[j] * bv);
    ovt[j] = f2bf(av[j]);
  }
  *(u16x4*)(qn + hoff) = oq;
  *(u16x4*)(kn + hoff) = ok;
  *(u16x4*)(kb + hoff) = okb;
  *(u16x4*)(vb + hoff) = ovb;
  *(u16x4*)(vtok + (size_t)t * 1024 + c) = ovt;
}

// ---------------------------------------------------------------------------
// per-(bh,chunk): X = (I + strict_tril(kb@kn^T))^-1 ; u=X@vb ; w=X@kb ;
// attn_loc = tril(qn@kn^T) ; kt = kn^T
// ---------------------------------------------------------------------------
__global__ __launch_bounds__(256) void k_chunkprep(const u16* __restrict__ qn, const u16* __restrict__ kn,
                                                   const u16* __restrict__ kb, const u16* __restrict__ vb,
                                                   u16* __restrict__ u, u16* __restrict__ w,
                                                   u16* __restrict__ attn_loc, u16* __restrict__ kt) {
  const int blk = blockIdx.x;  // bh*NC + chunk
  const int bh = blk >> 7, ch = blk & 127;
  const int tid = threadIdx.x;
  __shared__ u16 kbl[32 * 128], knl[32 * 128], vbl[32 * 128], qnl[32 * 128];
  __shared__ float Af[32][33];
  __shared__ float X[32][33];
  size_t base = ((size_t)bh * L_ + (size_t)ch * 32) * 128;
#pragma unroll
  for (int rep = 0; rep < 2; ++rep) {
    int lin = rep * 2048 + tid * 8;
    *(u16x8*)&kbl[lin] = *(const u16x8*)(kb + base + lin);
    *(u16x8*)&knl[lin] = *(const u16x8*)(kn + base + lin);
    *(u16x8*)&vbl[lin] = *(const u16x8*)(vb + base + lin);
    *(u16x8*)&qnl[lin] = *(const u16x8*)(qn + base + lin);
  }
  __syncthreads();
  {
    const int i = tid >> 3;
    const int j0 = (tid & 7) * 4;
    float a[4] = {0, 0, 0, 0};
    float q[4] = {0, 0, 0, 0};
    for (int d = 0; d < 128; ++d) {
      float kbi = bf2f(kbl[i * 128 + d]);
      float qni = bf2f(qnl[i * 128 + d]);
#pragma unroll
      for (int jj = 0; jj < 4; ++jj) {
        float knv = bf2f(knl[(j0 + jj) * 128 + d]);
        a[jj] += kbi * knv;
        q[jj] += qni * knv;
      }
    }
    size_t abase = (size_t)blk * 1024;
#pragma unroll
    for (int jj = 0; jj < 4; ++jj) {
      Af[i][j0 + jj] = a[jj];
      attn_loc[abase + i * 32 + j0 + jj] = f2bf((j0 + jj) <= i ? q[jj] : 0.f);
    }
  }
  __syncthreads();
  if (tid < 32) {
    int j = tid;  // column j of X, fully lane-local
    for (int i = 0; i < 32; ++i) X[i][j] = (i == j) ? 1.f : 0.f;
    for (int i = j + 1; i < 32; ++i) {
      float s = 0.f;
      for (int m = j; m < i; ++m) s += Af[i][m] * X[m][j];
      X[i][j] = -s;
    }
  }
  __syncthreads();
  {
    const int i = tid >> 3;
    const int d0 = (tid & 7) * 16;
    float ua[16], wa[16];
#pragma unroll
    for (int dd = 0; dd < 16; ++dd) { ua[dd] = 0.f; wa[dd] = 0.f; }
    for (int m = 0; m <= i; ++m) {  // X unit-lower: zero above diag
      float xv = X[i][m];
#pragma unroll
      for (int dd = 0; dd < 16; ++dd) {
        ua[dd] += xv * bf2f(vbl[m * 128 + d0 + dd]);
        wa[dd] += xv * bf2f(kbl[m * 128 + d0 + dd]);
      }
    }
#pragma unroll
    for (int part = 0; part < 2; ++part) {
      u16x8 su, sw;
#pragma unroll
      for (int e = 0; e < 8; ++e) {
        su[e] = f2bf(ua[part * 8 + e]);
        sw[e] = f2bf(wa[part * 8 + e]);
      }
      *(u16x8*)(u + base + (size_t)i * 128 + d0 + part * 8) = su;
      *(u16x8*)(w + base + (size_t)i * 128 + d0 + part * 8) = sw;
    }
  }
  {
    const size_t kbase = (size_t)blk * 4096;
    const int lin0 = tid * 16;
#pragma unroll
    for (int part = 0; part < 2; ++part) {
      u16x8 tv;
#pragma unroll
      for (int e = 0; e < 8; ++e) {
        int lin = lin0 + part * 8 + e;
        tv[e] = knl[(lin & 31) * 128 + (lin >> 5)];  // kt[dk][r] = kn[r][dk]
      }
      *(u16x8*)(kt + kbase + lin0 + part * 8) = tv;
    }
  }
}

// ---------------------------------------------------------------------------
// sequential inter-chunk scan; 1 wave per block; block = (bh, dv-slice of 16)
// S[128 x 16] kept in f32 MFMA accumulators
// ---------------------------------------------------------------------------
__global__ __launch_bounds__(64) void k_scan(const u16* __restrict__ qn, const u16* __restrict__ ktp,
                                             const u16* __restrict__ w, const u16* __restrict__ u,
                                             const u16* __restrict__ attn_loc, u16* __restrict__ o_out) {
  const int blk = blockIdx.x;  // 0..127
  const int bh = blk >> 3, s = blk & 7;
  const int c0 = s * 16;
  const int b = bh >> 3, h = bh & 7;
  const int lane = threadIdx.x;
  const int g = lane >> 4, li = lane & 15;
  __shared__ u16 S_t[16 * 136];  // transposed S (bf16): [col][row], padded stride 136 (272B, 16B-aligned)
  __shared__ u16 uf_t[16 * 40];  // transposed ufix: [col][row], stride 40 (80B)
  f32x4 S[8];
#pragma unroll
  for (int mi = 0; mi < 8; ++mi) S[mi] = (f32x4){0.f, 0.f, 0.f, 0.f};
  const u16* qb = qn + (size_t)bh * L_ * 128;
  const u16* wb = w + (size_t)bh * L_ * 128;
  const u16* ub = u + (size_t)bh * L_ * 128;
  const u16* ab = attn_loc + (size_t)bh * NC * 1024;
  const u16* kbase = ktp + (size_t)bh * NC * 4096;

  for (int ch = 0; ch < NC; ++ch) {
    // export S (f32 acc, C-layout) -> S_t bf16 transposed for B-fragment reads
#pragma unroll
    for (int mi = 0; mi < 8; ++mi) {
      u16x4 sv;
#pragma unroll
      for (int r = 0; r < 4; ++r) sv[r] = f2bf(S[mi][r]);
      *(u16x4*)&S_t[li * 136 + mi * 16 + g * 4] = sv;
    }
    bf16x8 bS[4];
#pragma unroll
    for (int ks = 0; ks < 4; ++ks)
      bS[ks] = *(const bf16x8*)&S_t[li * 136 + ks * 32 + g * 8];

    const u16* wc_ = wb + (size_t)ch * 4096;
    const u16* qc_ = qb + (size_t)ch * 4096;
    const u16* ac_ = ab + (size_t)ch * 1024;
    const u16* kc_ = kbase + (size_t)ch * 4096;
    const u16* uc_ = ub + (size_t)ch * 4096 + c0;

    // t1 = w_i @ S
    f32x4 t1[2];
    t1[0] = (f32x4){0.f, 0.f, 0.f, 0.f};
    t1[1] = (f32x4){0.f, 0.f, 0.f, 0.f};
#pragma unroll
    for (int mw = 0; mw < 2; ++mw)
#pragma unroll
      for (int ks = 0; ks < 4; ++ks) {
        bf16x8 aw = *(const bf16x8*)(wc_ + (size_t)(mw * 16 + li) * 128 + ks * 32 + g * 8);
        t1[mw] = __builtin_amdgcn_mfma_f32_16x16x32_bf16(aw, bS[ks], t1[mw], 0, 0, 0);
      }
    // ufix = u_i - t1  -> transposed LDS (B-fragment for K=32)
#pragma unroll
    for (int mw = 0; mw < 2; ++mw) {
      u16x4 ufv;
#pragma unroll
      for (int r = 0; r < 4; ++r) {
        int row = mw * 16 + g * 4 + r;
        float uval = bf2f(uc_[(size_t)row * 128 + li]);
        ufv[r] = f2bf(uval - t1[mw][r]);
      }
      *(u16x4*)&uf_t[li * 40 + mw * 16 + g * 4] = ufv;
    }
    bf16x8 bUF = *(const bf16x8*)&uf_t[li * 40 + g * 8];
    // o = q_i @ S + attn_i @ ufix
    f32x4 oa[2];
    oa[0] = (f32x4){0.f, 0.f, 0.f, 0.f};
    oa[1] = (f32x4){0.f, 0.f, 0.f, 0.f};
#pragma unroll
    for (int mw = 0; mw < 2; ++mw)
#pragma unroll
      for (int ks = 0; ks < 4; ++ks) {
        bf16x8 aq = *(const bf16x8*)(qc_ + (size_t)(mw * 16 + li) * 128 + ks * 32 + g * 8);
        oa[mw] = __builtin_amdgcn_mfma_f32_16x16x32_bf16(aq, bS[ks], oa[mw], 0, 0, 0);
      }
#pragma unroll
    for (int mw = 0; mw < 2; ++mw) {
      bf16x8 aat = *(const bf16x8*)(ac_ + (size_t)(mw * 16 + li) * 32 + g * 8);
      oa[mw] = __builtin_amdgcn_mfma_f32_16x16x32_bf16(aat, bUF, oa[mw], 0, 0, 0);
    }
    // write o (token-major)
#pragma unroll
    for (int mw = 0; mw < 2; ++mw)
#pragma unroll
      for (int r = 0; r < 4; ++r) {
        int row = mw * 16 + g * 4 + r;
        int tok = ch * 32 + row;
        o_out[((size_t)b * L_ + tok) * 1024 + h * 128 + c0 + li] = f2bf(oa[mw][r]);
      }
    // S += k_i^T @ ufix
#pragma unroll
    for (int mi = 0; mi < 8; ++mi) {
      bf16x8 akt = *(const bf16x8*)(kc_ + (size_t)(mi * 16 + li) * 32 + g * 8);
      S[mi] = __builtin_amdgcn_mfma_f32_16x16x32_bf16(akt, bUF, S[mi], 0, 0, 0);
    }
  }
}

// ---------------------------------------------------------------------------
// o = g*o + (1-g)*v_token ; RMS over DV ; * o_norm_w ; -> bf16 for final GEMM
// ---------------------------------------------------------------------------
__global__ __launch_bounds__(256) void k_mixnorm(const u16* __restrict__ o_mid, const u16* __restrict__ vtok,
                                                 const float* __restrict__ g, const float* __restrict__ onw,
                                                 u16* __restrict__ omix) {
  int t = blockIdx.x, tid = threadIdx.x;
  int c = tid * 4, h = c >> 7, dk = c & 127;
  float gv = g[t * 8 + h];
  u16x4 ov = *(const u16x4*)(o_mid + (size_t)t * 1024 + c);
  u16x4 vv = *(const u16x4*)(vtok + (size_t)t * 1024 + c);
  float mx[4];
#pragma unroll
  for (int j = 0; j < 4; ++j) mx[j] = gv * bf2f(ov[j]) + (1.f - gv) * bf2f(vv[j]);
  float ss = mx[0] * mx[0] + mx[1] * mx[1] + mx[2] * mx[2] + mx[3] * mx[3];
#pragma unroll
  for (int m = 1; m <= 16; m <<= 1) ss += __shfl_xor(ss, m);
  float r = rsqrtf(ss * (1.f / 128.f) + 1e-5f);
  u16x4 oo;
#pragma unroll
  for (int j = 0; j < 4; ++j) oo[j] = f2bf(mx[j] * r * onw[dk + j]);
  *(u16x4*)(omix + (size_t)t * 1024 + c) = oo;
}

// ---------------------------------------------------------------------------
extern "C" void kernel_launch(void* const* d_in, const int* in_sizes, int n_in,
                              void* d_out, int out_size, void* d_ws, size_t ws_size,
                              hipStream_t stream) {
  const float* hidden = (const float*)d_in[0];
  const float* q_w = (const float*)d_in[1];
  const float* k_w = (const float*)d_in[2];
  const float* v_w = (const float*)d_in[3];
  const float* cqw = (const float*)d_in[4];
  const float* ckw = (const float*)d_in[5];
  const float* cvw = (const float*)d_in[6];
  const float* b_w = (const float*)d_in[7];
  const float* mix_w = (const float*)d_in[8];
  const float* mix_b = (const float*)d_in[9];
  const float* mix_bias = (const float*)d_in[10];
  const float* onw = (const float*)d_in[11];
  const float* o_w = (const float*)d_in[12];

  char* ws = (char*)d_ws;
  size_t off = 0;
  auto alloc = [&](size_t bytes) {
    char* p = ws + off;
    off += (bytes + 255) & ~(size_t)255;
    return p;
  };
  u16* hbf = (u16*)alloc(16777216);    // hidden bf16; reused as omix at the end
  u16* wqT = (u16*)alloc(2097152);
  u16* wkT = (u16*)alloc(2097152);
  u16* wvT = (u16*)alloc(2097152);
  u16* woT = (u16*)alloc(2097152);
  u16* qraw = (u16*)alloc(16777216);   // reused as u after conv
  u16* kraw = (u16*)alloc(16777216);   // reused as w after conv
  u16* vraw = (u16*)alloc(16777216);   // reused as o (scan output) after conv
  float* beta = (float*)alloc(262144);
  float* gg = (float*)alloc(262144);
  u16* qn = (u16*)alloc(16777216);
  u16* kn = (u16*)alloc(16777216);
  u16* kbn = (u16*)alloc(16777216);
  u16* vbn = (u16*)alloc(16777216);
  u16* vtok = (u16*)alloc(16777216);
  u16* attn = (u16*)alloc(4194304);
  u16* ktp = (u16*)alloc(16777216);
  if (off > ws_size) return;  // workspace too small: leave output untouched (visible as stub-like absmax)

  u16* ubuf = qraw;
  u16* wbuf = kraw;
  u16* obuf = vraw;

  k_f32_to_bf16<<<8192, 256, 0, stream>>>(hidden, hbf, 2097152);
  k_transpose_w<<<dim3(32, 32, 4), 256, 0, stream>>>(q_w, k_w, v_w, o_w, wqT, wkT, wvT, woT);
  k_beta_g<<<256, 256, 0, stream>>>(hidden, b_w, mix_w, mix_b, mix_bias, beta, gg);
  dim3 gemm_grid(8, 64);
  gemm_bt<true><<<gemm_grid, 256, 0, stream>>>(hbf, wqT, qraw, BL, 1024, 1024);
  gemm_bt<true><<<gemm_grid, 256, 0, stream>>>(hbf, wkT, kraw, BL, 1024, 1024);
  gemm_bt<true><<<gemm_grid, 256, 0, stream>>>(hbf, wvT, vraw, BL, 1024, 1024);
  k_conv<<<8192, 256, 0, stream>>>(qraw, kraw, vraw, cqw, ckw, cvw, beta, qn, kn, kbn, vbn, vtok);
  k_chunkprep<<<2048, 256, 0, stream>>>(qn, kn, kbn, vbn, ubuf, wbuf, attn, ktp);
  k_scan<<<128, 64, 0, stream>>>(qn, ktp, wbuf, ubuf, attn, obuf);
  k_mixnorm<<<8192, 256, 0, stream>>>(obuf, vtok, gg, onw, hbf);
  gemm_bt<false><<<gemm_grid, 256, 0, stream>>>(hbf, woT, d_out, BL, 1024, 1024);
}

// Round 2
// 734.666 us; speedup vs baseline: 1.5268x; 1.5268x over previous
//
#include <hip/hip_runtime.h>
#include <cstdint>
#include <cstddef>

typedef unsigned short u16;
typedef unsigned int u32;
typedef __attribute__((ext_vector_type(4))) u16 u16x4;
typedef __attribute__((ext_vector_type(8))) u16 u16x8;
typedef __attribute__((ext_vector_type(4))) float f32x4;
typedef __attribute__((ext_vector_type(8))) __bf16 bf16x8;

#define DEV static __device__ __forceinline__

DEV u16 f2bf(float f) {
  u32 u = __builtin_bit_cast(u32, f);
  u32 r = (u + 0x7FFFu + ((u >> 16) & 1u)) >> 16;
  return (u16)r;
}
DEV float bf2f(u16 s) { return __builtin_bit_cast(float, (u32)s << 16); }

DEV void gl_lds16(const void* g, void* l) {
  __builtin_amdgcn_global_load_lds((const __attribute__((address_space(1))) u32*)g,
                                   (__attribute__((address_space(3))) u32*)l, 16, 0, 0);
}

constexpr int B_ = 2, L_ = 4096, H_ = 8;
constexpr int BL = B_ * L_;   // 8192 tokens
constexpr int NC = L_ / 32;   // 128 chunks per sequence

// blob layout per (bh,chunk), u16 element offsets; total 17408 elems = 34816 B
constexpr int WOFF = 0;       // w   A-frags: ((mw*4+ks)*64 + lane)*8 + e
constexpr int QOFF = 4096;    // q   A-frags: same mapping
constexpr int KTOFF = 8192;   // k^T A-frags: (mi*64 + lane)*8 + e
constexpr int AOFF = 12288;   // attn A-frags: (mw*64 + lane)*8 + e
constexpr int UTOFF = 13312;  // u^T  frags: ((s*2+mw)*64 + lane)*4 + r
constexpr int BLOB_ELEMS = 17408;

// ---------------------------------------------------------------------------
// f32 -> bf16 convert (hidden)
// ---------------------------------------------------------------------------
__global__ __launch_bounds__(256) void k_f32_to_bf16(const float* __restrict__ src,
                                                     u16* __restrict__ dst, int n4) {
  int i = blockIdx.x * 256 + threadIdx.x;
  if (i < n4) {
    f32x4 v = *(const f32x4*)(src + (size_t)i * 4);
    u16x4 o;
#pragma unroll
    for (int j = 0; j < 4; ++j) o[j] = f2bf(v[j]);
    *(u16x4*)(dst + (size_t)i * 4) = o;
  }
}

// ---------------------------------------------------------------------------
// transpose 1024x1024 f32 weights -> bf16 [n][k]
// ---------------------------------------------------------------------------
__global__ __launch_bounds__(256) void k_transpose_w(const float* __restrict__ s0, const float* __restrict__ s1,
                                                     const float* __restrict__ s2, const float* __restrict__ s3,
                                                     u16* __restrict__ d0, u16* __restrict__ d1,
                                                     u16* __restrict__ d2, u16* __restrict__ d3) {
  const float* src = blockIdx.z == 0 ? s0 : blockIdx.z == 1 ? s1 : blockIdx.z == 2 ? s2 : s3;
  u16* dst = blockIdx.z == 0 ? d0 : blockIdx.z == 1 ? d1 : blockIdx.z == 2 ? d2 : d3;
  __shared__ float tile[32][33];
  int k0 = blockIdx.y * 32, n0 = blockIdx.x * 32;
  int ty = threadIdx.x >> 5, tx = threadIdx.x & 31;
#pragma unroll
  for (int i = 0; i < 4; ++i)
    tile[ty + 8 * i][tx] = src[(size_t)(k0 + ty + 8 * i) * 1024 + n0 + tx];
  __syncthreads();
#pragma unroll
  for (int i = 0; i < 4; ++i) {
    int nl = ty + 8 * i;
    dst[(size_t)(n0 + nl) * 1024 + k0 + tx] = f2bf(tile[tx][nl]);
  }
}

// ---------------------------------------------------------------------------
// bf16 GEMM: C[M,N] = A[M,K] * Bt[N,K]^T ; 128x128 tile, 4 waves, 16x16x32 MFMA
// staging via global_load_lds width-16 (lane-linear dest, source k-swizzled)
// ---------------------------------------------------------------------------
template<bool STORE_BF16>
__global__ __launch_bounds__(256) void gemm_bt(const u16* __restrict__ A, const u16* __restrict__ Bt,
                                               void* __restrict__ Cout, int M, int N, int K) {
  __shared__ u16 Ash[128 * 32];
  __shared__ u16 Bsh[128 * 32];
  const int tid = threadIdx.x;
  const int lane = tid & 63, w = tid >> 6;
  const int wr = w >> 1, wc = w & 1;
  const int g = lane >> 4, li = lane & 15;
  const int mblk = blockIdx.y * 128, nblk = blockIdx.x * 128;
  const int srow = tid >> 2, sslot = tid & 3;

  f32x4 acc[4][4];
#pragma unroll
  for (int m = 0; m < 4; ++m)
#pragma unroll
    for (int n = 0; n < 4; ++n) acc[m][n] = (f32x4){0.f, 0.f, 0.f, 0.f};

  for (int kt = 0; kt < K; kt += 32) {
    __syncthreads();
#pragma unroll
    for (int half = 0; half < 2; ++half) {
      int row = srow + half * 64;
      int gk = kt + ((sslot ^ (row & 3)) << 3);  // XOR-swizzled source k-group
      gl_lds16(A + (size_t)(mblk + row) * K + gk, (char*)Ash + tid * 16 + half * 4096);
      gl_lds16(Bt + (size_t)(nblk + row) * K + gk, (char*)Bsh + tid * 16 + half * 4096);
    }
    __syncthreads();
    bf16x8 af[4], bfr[4];
#pragma unroll
    for (int m = 0; m < 4; ++m) {
      int row = wr * 64 + m * 16 + li;
      af[m] = *(const bf16x8*)&Ash[row * 32 + ((g ^ (li & 3)) << 3)];
    }
#pragma unroll
    for (int n = 0; n < 4; ++n) {
      int row = wc * 64 + n * 16 + li;
      bfr[n] = *(const bf16x8*)&Bsh[row * 32 + ((g ^ (li & 3)) << 3)];
    }
#pragma unroll
    for (int m = 0; m < 4; ++m)
#pragma unroll
      for (int n = 0; n < 4; ++n)
        acc[m][n] = __builtin_amdgcn_mfma_f32_16x16x32_bf16(af[m], bfr[n], acc[m][n], 0, 0, 0);
  }
#pragma unroll
  for (int m = 0; m < 4; ++m)
#pragma unroll
    for (int n = 0; n < 4; ++n)
#pragma unroll
      for (int r = 0; r < 4; ++r) {
        int grow = mblk + wr * 64 + m * 16 + g * 4 + r;
        int gcol = nblk + wc * 64 + n * 16 + li;
        if constexpr (STORE_BF16)
          ((u16*)Cout)[(size_t)grow * N + gcol] = f2bf(acc[m][n][r]);
        else
          ((float*)Cout)[(size_t)grow * N + gcol] = acc[m][n][r];
      }
}

// ---------------------------------------------------------------------------
// beta = sigmoid(hidden @ b_w) ; g = sigmoid(hidden @ mix_w + mix_b + mix_bias)
// ---------------------------------------------------------------------------
__global__ __launch_bounds__(256) void k_beta_g(const float* __restrict__ hidden, const float* __restrict__ b_w,
                                                const float* __restrict__ mix_w, const float* __restrict__ mix_b,
                                                const float* __restrict__ mix_bias,
                                                float* __restrict__ beta, float* __restrict__ g) {
  int idx = blockIdx.x * 256 + threadIdx.x;  // 0..65535 : (token, head)
  int t = idx >> 3, h = idx & 7;
  const f32x4* hrow = (const f32x4*)(hidden + (size_t)t * 1024);
  float sb = 0.f, sg = 0.f;
  for (int d4 = 0; d4 < 256; ++d4) {
    f32x4 hv = hrow[d4];
    int d = d4 * 4;
#pragma unroll
    for (int j = 0; j < 4; ++j) {
      sb += hv[j] * b_w[(d + j) * 8 + h];
      sg += hv[j] * mix_w[(d + j) * 8 + h];
    }
  }
  beta[idx] = 1.f / (1.f + expf(-sb));
  float gz = sg + mix_b[h] + mix_bias[h];
  g[idx] = 1.f / (1.f + expf(-gz));
}

// ---------------------------------------------------------------------------
// causal depthwise conv(K=4) + SiLU + per-head l2norm(q,k) + beta scaling
// ---------------------------------------------------------------------------
__global__ __launch_bounds__(256) void k_conv(const u16* __restrict__ qraw, const u16* __restrict__ kraw,
                                              const u16* __restrict__ vraw,
                                              const float* __restrict__ cqw, const float* __restrict__ ckw,
                                              const float* __restrict__ cvw, const float* __restrict__ beta,
                                              u16* __restrict__ qn, u16* __restrict__ kn, u16* __restrict__ kb,
                                              u16* __restrict__ vb, u16* __restrict__ vtok) {
  const int t = blockIdx.x;
  const int l = t & (L_ - 1);
  const int b = t >> 12;
  const int tid = threadIdx.x;
  const int c = tid * 4;
  const int h = c >> 7, dk = c & 127;
  float aq[4] = {0, 0, 0, 0}, ak[4] = {0, 0, 0, 0}, av[4] = {0, 0, 0, 0};
#pragma unroll
  for (int i = 0; i < 4; ++i) {
    int lr = l - 3 + i;
    if (lr < 0) continue;
    size_t off = (size_t)(t - 3 + i) * 1024 + c;
    u16x4 xq = *(const u16x4*)(qraw + off);
    u16x4 xk = *(const u16x4*)(kraw + off);
    u16x4 xv = *(const u16x4*)(vraw + off);
#pragma unroll
    for (int j = 0; j < 4; ++j) {
      aq[j] += bf2f(xq[j]) * cqw[(c + j) * 4 + i];
      ak[j] += bf2f(xk[j]) * ckw[(c + j) * 4 + i];
      av[j] += bf2f(xv[j]) * cvw[(c + j) * 4 + i];
    }
  }
#pragma unroll
  for (int j = 0; j < 4; ++j) {
    aq[j] = aq[j] / (1.f + expf(-aq[j]));
    ak[j] = ak[j] / (1.f + expf(-ak[j]));
    av[j] = av[j] / (1.f + expf(-av[j]));
  }
  float sq = aq[0] * aq[0] + aq[1] * aq[1] + aq[2] * aq[2] + aq[3] * aq[3];
  float sk = ak[0] * ak[0] + ak[1] * ak[1] + ak[2] * ak[2] + ak[3] * ak[3];
#pragma unroll
  for (int m = 1; m <= 16; m <<= 1) {
    sq += __shfl_xor(sq, m);
    sk += __shfl_xor(sk, m);
  }
  float rq = rsqrtf(sq + 1e-12f), rk = rsqrtf(sk + 1e-12f);
  float bv = beta[t * 8 + h];
  size_t hoff = ((size_t)(b * 8 + h) * L_ + l) * 128 + dk;
  u16x4 oq, ok, okb, ovb, ovt;
#pragma unroll
  for (int j = 0; j < 4; ++j) {
    float kq = aq[j] * rq;
    float kk = ak[j] * rk;
    oq[j] = f2bf(kq);
    ok[j] = f2bf(kk);
    okb[j] = f2bf(kk * bv);
    ovb[j] = f2bf(av[j] * bv);
    ovt[j] = f2bf(av[j]);
  }
  *(u16x4*)(qn + hoff) = oq;
  *(u16x4*)(kn + hoff) = ok;
  *(u16x4*)(kb + hoff) = okb;
  *(u16x4*)(vb + hoff) = ovb;
  *(u16x4*)(vtok + (size_t)t * 1024 + c) = ovt;
}

// ---------------------------------------------------------------------------
// per-(bh,chunk): X = (I + strict_tril(kb@kn^T))^-1 ; u=X@vb ; w=X@kb ;
// attn = tril(qn@kn^T). Outputs packed in MFMA-fragment blob for the scan.
// ---------------------------------------------------------------------------
__global__ __launch_bounds__(256) void k_chunkprep(const u16* __restrict__ qn, const u16* __restrict__ kn,
                                                   const u16* __restrict__ kb, const u16* __restrict__ vb,
                                                   u16* __restrict__ blob) {
  const int blk = blockIdx.x;  // bh*NC + chunk
  const int bh = blk >> 7, ch = blk & 127;
  const int tid = threadIdx.x;
  __shared__ u16 kbl[4096], knl[4096], vbl[4096], qnl[4096];
  __shared__ float Af[32][33];
  __shared__ float X[32][33];
  __shared__ u16 w_s[4096], u_s[4096], attn_s[1024];
  size_t base = ((size_t)bh * L_ + (size_t)ch * 32) * 128;
#pragma unroll
  for (int rep = 0; rep < 2; ++rep) {
    int lin = rep * 2048 + tid * 8;
    *(u16x8*)&kbl[lin] = *(const u16x8*)(kb + base + lin);
    *(u16x8*)&knl[lin] = *(const u16x8*)(kn + base + lin);
    *(u16x8*)&vbl[lin] = *(const u16x8*)(vb + base + lin);
    *(u16x8*)&qnl[lin] = *(const u16x8*)(qn + base + lin);
  }
  __syncthreads();
  {
    const int i = tid >> 3;
    const int j0 = (tid & 7) * 4;
    float a[4] = {0, 0, 0, 0};
    float q[4] = {0, 0, 0, 0};
    for (int d = 0; d < 128; ++d) {
      float kbi = bf2f(kbl[i * 128 + d]);
      float qni = bf2f(qnl[i * 128 + d]);
#pragma unroll
      for (int jj = 0; jj < 4; ++jj) {
        float knv = bf2f(knl[(j0 + jj) * 128 + d]);
        a[jj] += kbi * knv;
        q[jj] += qni * knv;
      }
    }
#pragma unroll
    for (int jj = 0; jj < 4; ++jj) {
      Af[i][j0 + jj] = a[jj];
      attn_s[i * 32 + j0 + jj] = f2bf((j0 + jj) <= i ? q[jj] : 0.f);
    }
  }
  __syncthreads();
  if (tid < 32) {
    int j = tid;  // column j of X, fully lane-local
    for (int i = 0; i < 32; ++i) X[i][j] = (i == j) ? 1.f : 0.f;
    for (int i = j + 1; i < 32; ++i) {
      float s = 0.f;
      for (int m = j; m < i; ++m) s += Af[i][m] * X[m][j];
      X[i][j] = -s;
    }
  }
  __syncthreads();
  {
    const int i = tid >> 3;
    const int d0 = (tid & 7) * 16;
    float ua[16], wa[16];
#pragma unroll
    for (int dd = 0; dd < 16; ++dd) { ua[dd] = 0.f; wa[dd] = 0.f; }
    for (int m = 0; m <= i; ++m) {
      float xv = X[i][m];
#pragma unroll
      for (int dd = 0; dd < 16; ++dd) {
        ua[dd] += xv * bf2f(vbl[m * 128 + d0 + dd]);
        wa[dd] += xv * bf2f(kbl[m * 128 + d0 + dd]);
      }
    }
#pragma unroll
    for (int part = 0; part < 2; ++part) {
      u16x8 su, sw;
#pragma unroll
      for (int e = 0; e < 8; ++e) {
        su[e] = f2bf(ua[part * 8 + e]);
        sw[e] = f2bf(wa[part * 8 + e]);
      }
      *(u16x8*)&u_s[i * 128 + d0 + part * 8] = su;
      *(u16x8*)&w_s[i * 128 + d0 + part * 8] = sw;
    }
  }
  __syncthreads();
  // ---- blob assembly (fragment order; 16B vector writes, coalesced) ----
  u16* bp = blob + (size_t)blk * BLOB_ELEMS;
#pragma unroll
  for (int it = 0; it < 2; ++it) {
    const int v8 = tid * 2 + it;  // 0..511
    const int f = v8 >> 6, l = v8 & 63;
    const int li = l & 15, g = l >> 4;
    {  // w and q A-fragments
      int mw = f >> 2, ks = f & 3;
      int row = mw * 16 + li, c0 = ks * 32 + g * 8;
      *(u16x8*)(bp + WOFF + (size_t)v8 * 8) = *(const u16x8*)&w_s[row * 128 + c0];
      *(u16x8*)(bp + QOFF + (size_t)v8 * 8) = *(const u16x8*)&qnl[row * 128 + c0];
    }
    {  // kt A-fragments: kt[dk][c] = kn[c][dk]
      int dk = f * 16 + li, c0 = g * 8;
      u16x8 tv;
#pragma unroll
      for (int e = 0; e < 8; ++e) tv[e] = knl[(c0 + e) * 128 + dk];
      *(u16x8*)(bp + KTOFF + (size_t)v8 * 8) = tv;
    }
    {  // u^T fragments: ((s*2+mw)*64 + l)*4 + r  = u[mw*16+g*4+r][s*16+li]
      int smw = v8 >> 5, l0 = (v8 * 2) & 63;
      int s_ = smw >> 1, mw = smw & 1;
      u16x8 tv;
#pragma unroll
      for (int half = 0; half < 2; ++half) {
        int ll = l0 + half, lli = ll & 15, lg = ll >> 4;
#pragma unroll
        for (int r = 0; r < 4; ++r)
          tv[half * 4 + r] = u_s[(mw * 16 + lg * 4 + r) * 128 + s_ * 16 + lli];
      }
      *(u16x8*)(bp + UTOFF + (size_t)v8 * 8) = tv;
    }
  }
  if (tid < 128) {  // attn A-fragments
    const int v8 = tid;
    const int mw = v8 >> 6, l = v8 & 63;
    const int li = l & 15, g = l >> 4;
    *(u16x8*)(bp + AOFF + (size_t)v8 * 8) = *(const u16x8*)&attn_s[(mw * 16 + li) * 32 + g * 8];
  }
}

// ---------------------------------------------------------------------------
// sequential inter-chunk scan; 1 block per (b,h); 8 waves = 8 dv-slices of 16.
// Per-chunk operands double-buffered in LDS via global_load_lds (prefetch).
// ---------------------------------------------------------------------------
DEV void stage_blob(const u16* g, u16* l, int tid) {
#pragma unroll
  for (int it = 0; it < 4; ++it) {
    int off = it * 8192 + tid * 16;
    gl_lds16((const char*)g + off, (char*)l + off);
  }
  if (tid < 128) {
    int off = 32768 + tid * 16;
    gl_lds16((const char*)g + off, (char*)l + off);
  }
}

__global__ __launch_bounds__(512) void k_scan(const u16* __restrict__ blob, u16* __restrict__ o_out) {
  __shared__ u16 lds[2 * BLOB_ELEMS + 8 * 2176 + 8 * 640];  // 112 KiB
  const int bh = blockIdx.x;  // 0..15
  const int b = bh >> 3, h = bh & 7;
  const int tid = threadIdx.x;
  const int s = tid >> 6, lane = tid & 63;
  const int g = lane >> 4, li = lane & 15;
  const int c0 = s * 16;
  u16* buf0 = lds;
  u16* buf1 = lds + BLOB_ELEMS;
  u16* st = lds + 2 * BLOB_ELEMS + s * 2176;          // per-wave S_t [16][136]
  u16* uft = lds + 2 * BLOB_ELEMS + 8 * 2176 + s * 640;  // per-wave uf_t [16][40]

  f32x4 S[8];
#pragma unroll
  for (int mi = 0; mi < 8; ++mi) S[mi] = (f32x4){0.f, 0.f, 0.f, 0.f};

  const u16* gb = blob + (size_t)bh * NC * BLOB_ELEMS;
  stage_blob(gb, buf0, tid);
  __syncthreads();

  for (int ch = 0; ch < NC; ++ch) {
    const u16* bp = (ch & 1) ? buf1 : buf0;
    if (ch + 1 < NC) stage_blob(gb + (size_t)(ch + 1) * BLOB_ELEMS, (ch & 1) ? buf0 : buf1, tid);

    // export S (f32 acc, C-layout) -> bf16 transposed, read back as B-frags
#pragma unroll
    for (int mi = 0; mi < 8; ++mi) {
      u16x4 sv;
#pragma unroll
      for (int r = 0; r < 4; ++r) sv[r] = f2bf(S[mi][r]);
      *(u16x4*)&st[li * 136 + mi * 16 + g * 4] = sv;
    }
    bf16x8 bS[4];
#pragma unroll
    for (int ks = 0; ks < 4; ++ks)
      bS[ks] = *(const bf16x8*)&st[li * 136 + ks * 32 + g * 8];

    // t1 = w_i @ S
    f32x4 t1[2];
    t1[0] = (f32x4){0.f, 0.f, 0.f, 0.f};
    t1[1] = (f32x4){0.f, 0.f, 0.f, 0.f};
#pragma unroll
    for (int mw = 0; mw < 2; ++mw)
#pragma unroll
      for (int ks = 0; ks < 4; ++ks) {
        bf16x8 aw = *(const bf16x8*)&bp[WOFF + ((size_t)((mw * 4 + ks) * 64 + lane)) * 8];
        t1[mw] = __builtin_amdgcn_mfma_f32_16x16x32_bf16(aw, bS[ks], t1[mw], 0, 0, 0);
      }
    // ufix = u_i - t1 -> per-wave transposed LDS -> B-frag
#pragma unroll
    for (int mw = 0; mw < 2; ++mw) {
      u16x4 uv = *(const u16x4*)&bp[UTOFF + ((size_t)((s * 2 + mw) * 64 + lane)) * 4];
      u16x4 ufv;
#pragma unroll
      for (int r = 0; r < 4; ++r) ufv[r] = f2bf(bf2f(uv[r]) - t1[mw][r]);
      *(u16x4*)&uft[li * 40 + mw * 16 + g * 4] = ufv;
    }
    bf16x8 bUF = *(const bf16x8*)&uft[li * 40 + g * 8];

    // o = q_i @ S + attn_i @ ufix
    f32x4 oa[2];
    oa[0] = (f32x4){0.f, 0.f, 0.f, 0.f};
    oa[1] = (f32x4){0.f, 0.f, 0.f, 0.f};
#pragma unroll
    for (int mw = 0; mw < 2; ++mw)
#pragma unroll
      for (int ks = 0; ks < 4; ++ks) {
        bf16x8 aq = *(const bf16x8*)&bp[QOFF + ((size_t)((mw * 4 + ks) * 64 + lane)) * 8];
        oa[mw] = __builtin_amdgcn_mfma_f32_16x16x32_bf16(aq, bS[ks], oa[mw], 0, 0, 0);
      }
#pragma unroll
    for (int mw = 0; mw < 2; ++mw) {
      bf16x8 aat = *(const bf16x8*)&bp[AOFF + ((size_t)(mw * 64 + lane)) * 8];
      oa[mw] = __builtin_amdgcn_mfma_f32_16x16x32_bf16(aat, bUF, oa[mw], 0, 0, 0);
    }
    // write o (token-major)
#pragma unroll
    for (int mw = 0; mw < 2; ++mw)
#pragma unroll
      for (int r = 0; r < 4; ++r) {
        int row = mw * 16 + g * 4 + r;
        int tok = ch * 32 + row;
        o_out[((size_t)b * L_ + tok) * 1024 + h * 128 + c0 + li] = f2bf(oa[mw][r]);
      }
    // S += k_i^T @ ufix
#pragma unroll
    for (int mi = 0; mi < 8; ++mi) {
      bf16x8 akt = *(const bf16x8*)&bp[KTOFF + ((size_t)(mi * 64 + lane)) * 8];
      S[mi] = __builtin_amdgcn_mfma_f32_16x16x32_bf16(akt, bUF, S[mi], 0, 0, 0);
    }
    __syncthreads();  // prefetch landed (vmcnt0) + all waves done with bp
  }
}

// ---------------------------------------------------------------------------
// o = g*o + (1-g)*v_token ; RMS over DV ; * o_norm_w ; -> bf16 for final GEMM
// ---------------------------------------------------------------------------
__global__ __launch_bounds__(256) void k_mixnorm(const u16* __restrict__ o_mid, const u16* __restrict__ vtok,
                                                 const float* __restrict__ g, const float* __restrict__ onw,
                                                 u16* __restrict__ omix) {
  int t = blockIdx.x, tid = threadIdx.x;
  int c = tid * 4, h = c >> 7, dk = c & 127;
  float gv = g[t * 8 + h];
  u16x4 ov = *(const u16x4*)(o_mid + (size_t)t * 1024 + c);
  u16x4 vv = *(const u16x4*)(vtok + (size_t)t * 1024 + c);
  float mx[4];
#pragma unroll
  for (int j = 0; j < 4; ++j) mx[j] = gv * bf2f(ov[j]) + (1.f - gv) * bf2f(vv[j]);
  float ss = mx[0] * mx[0] + mx[1] * mx[1] + mx[2] * mx[2] + mx[3] * mx[3];
#pragma unroll
  for (int m = 1; m <= 16; m <<= 1) ss += __shfl_xor(ss, m);
  float r = rsqrtf(ss * (1.f / 128.f) + 1e-5f);
  u16x4 oo;
#pragma unroll
  for (int j = 0; j < 4; ++j) oo[j] = f2bf(mx[j] * r * onw[dk + j]);
  *(u16x4*)(omix + (size_t)t * 1024 + c) = oo;
}

// ---------------------------------------------------------------------------
extern "C" void kernel_launch(void* const* d_in, const int* in_sizes, int n_in,
                              void* d_out, int out_size, void* d_ws, size_t ws_size,
                              hipStream_t stream) {
  const float* hidden = (const float*)d_in[0];
  const float* q_w = (const float*)d_in[1];
  const float* k_w = (const float*)d_in[2];
  const float* v_w = (const float*)d_in[3];
  const float* cqw = (const float*)d_in[4];
  const float* ckw = (const float*)d_in[5];
  const float* cvw = (const float*)d_in[6];
  const float* b_w = (const float*)d_in[7];
  const float* mix_w = (const float*)d_in[8];
  const float* mix_b = (const float*)d_in[9];
  const float* mix_bias = (const float*)d_in[10];
  const float* onw = (const float*)d_in[11];
  const float* o_w = (const float*)d_in[12];

  char* ws = (char*)d_ws;
  size_t off = 0;
  auto alloc = [&](size_t bytes) {
    char* p = ws + off;
    off += (bytes + 255) & ~(size_t)255;
    return p;
  };
  u16* hbf = (u16*)alloc(16777216);    // hidden bf16; reused as omix at the end
  u16* wqT = (u16*)alloc(2097152);
  u16* wkT = (u16*)alloc(2097152);
  u16* wvT = (u16*)alloc(2097152);
  u16* woT = (u16*)alloc(2097152);
  float* beta = (float*)alloc(262144);
  float* gg = (float*)alloc(262144);
  u16* qn = (u16*)alloc(16777216);     // reused as scan output o after chunkprep
  u16* kn = (u16*)alloc(16777216);
  u16* kbn = (u16*)alloc(16777216);
  u16* vbn = (u16*)alloc(16777216);
  u16* vtok = (u16*)alloc(16777216);
  u16* blob = (u16*)alloc(71303168);   // 16 bh * 128 ch * 34816 B (fragment blob)
  if (off > ws_size) return;

  // GEMM outputs / conv inputs live in the (not-yet-written) blob region
  u16* qraw = blob;
  u16* kraw = blob + 8388608;
  u16* vraw = blob + 16777216;
  u16* obuf = qn;  // scan output aliases qn (dead after chunkprep)

  k_f32_to_bf16<<<8192, 256, 0, stream>>>(hidden, hbf, 2097152);
  k_transpose_w<<<dim3(32, 32, 4), 256, 0, stream>>>(q_w, k_w, v_w, o_w, wqT, wkT, wvT, woT);
  k_beta_g<<<256, 256, 0, stream>>>(hidden, b_w, mix_w, mix_b, mix_bias, beta, gg);
  dim3 gemm_grid(8, 64);
  gemm_bt<true><<<gemm_grid, 256, 0, stream>>>(hbf, wqT, qraw, BL, 1024, 1024);
  gemm_bt<true><<<gemm_grid, 256, 0, stream>>>(hbf, wkT, kraw, BL, 1024, 1024);
  gemm_bt<true><<<gemm_grid, 256, 0, stream>>>(hbf, wvT, vraw, BL, 1024, 1024);
  k_conv<<<8192, 256, 0, stream>>>(qraw, kraw, vraw, cqw, ckw, cvw, beta, qn, kn, kbn, vbn, vtok);
  k_chunkprep<<<2048, 256, 0, stream>>>(qn, kn, kbn, vbn, blob);
  k_scan<<<16, 512, 0, stream>>>(blob, obuf);
  k_mixnorm<<<8192, 256, 0, stream>>>(obuf, vtok, gg, onw, hbf);
  gemm_bt<false><<<gemm_grid, 256, 0, stream>>>(hbf, woT, d_out, BL, 1024, 1024);
}

// Round 3
// 603.283 us; speedup vs baseline: 1.8593x; 1.2178x over previous
//
#include <hip/hip_runtime.h>
#include <cstdint>
#include <cstddef>

typedef unsigned short u16;
typedef unsigned int u32;
typedef __attribute__((ext_vector_type(4))) u16 u16x4;
typedef __attribute__((ext_vector_type(8))) u16 u16x8;
typedef __attribute__((ext_vector_type(4))) float f32x4;
typedef __attribute__((ext_vector_type(8))) __bf16 bf16x8;

#define DEV static __device__ __forceinline__

DEV u16 f2bf(float f) {  // HW RTNE convert (v_cvt_pk_bf16_f32)
  __bf16 h = (__bf16)f;
  return __builtin_bit_cast(u16, h);
}
DEV float bf2f(u16 s) { return __builtin_bit_cast(float, (u32)s << 16); }

DEV void gl_lds16(const void* g, void* l) {
  __builtin_amdgcn_global_load_lds((const __attribute__((address_space(1))) u32*)g,
                                   (__attribute__((address_space(3))) u32*)l, 16, 0, 0);
}

constexpr int B_ = 2, L_ = 4096, H_ = 8;
constexpr int BL = B_ * L_;   // 8192 tokens
constexpr int NC = L_ / 32;   // 128 chunks per sequence
constexpr int QKV_N = 3200;   // 3*1024 qkv + 16 beta/mix logit cols + 112 pad

// blob layout per (bh,chunk), u16 element offsets; total 17408 elems = 34816 B
constexpr int WOFF = 0;       // w   A-frags: ((mw*4+ks)*64 + lane)*8 + e
constexpr int QOFF = 4096;    // q   A-frags: same mapping
constexpr int KTOFF = 8192;   // k^T A-frags: (mi*64 + lane)*8 + e
constexpr int AOFF = 12288;   // attn A-frags: (mw*64 + lane)*8 + e
constexpr int UTOFF = 13312;  // u^T  frags: ((sg*2+mw)*64 + lane)*4 + r
constexpr int BLOB_ELEMS = 17408;

// ---------------------------------------------------------------------------
__global__ __launch_bounds__(256) void k_f32_to_bf16(const float* __restrict__ src,
                                                     u16* __restrict__ dst, int n4) {
  int i = blockIdx.x * 256 + threadIdx.x;
  if (i < n4) {
    f32x4 v = *(const f32x4*)(src + (size_t)i * 4);
    u16x4 o;
#pragma unroll
    for (int j = 0; j < 4; ++j) o[j] = f2bf(v[j]);
    *(u16x4*)(dst + (size_t)i * 4) = o;
  }
}

// ---------------------------------------------------------------------------
// transpose 1024x1024 f32 weights -> bf16 [n][k]; q,k,v go into one [3200][1024]
// ---------------------------------------------------------------------------
__global__ __launch_bounds__(256) void k_transpose_w(const float* __restrict__ s0, const float* __restrict__ s1,
                                                     const float* __restrict__ s2, const float* __restrict__ s3,
                                                     u16* __restrict__ d0, u16* __restrict__ d1,
                                                     u16* __restrict__ d2, u16* __restrict__ d3) {
  const float* src = blockIdx.z == 0 ? s0 : blockIdx.z == 1 ? s1 : blockIdx.z == 2 ? s2 : s3;
  u16* dst = blockIdx.z == 0 ? d0 : blockIdx.z == 1 ? d1 : blockIdx.z == 2 ? d2 : d3;
  __shared__ float tile[32][33];
  int k0 = blockIdx.y * 32, n0 = blockIdx.x * 32;
  int ty = threadIdx.x >> 5, tx = threadIdx.x & 31;
#pragma unroll
  for (int i = 0; i < 4; ++i)
    tile[ty + 8 * i][tx] = src[(size_t)(k0 + ty + 8 * i) * 1024 + n0 + tx];
  __syncthreads();
#pragma unroll
  for (int i = 0; i < 4; ++i) {
    int nl = ty + 8 * i;
    dst[(size_t)(n0 + nl) * 1024 + k0 + tx] = f2bf(tile[tx][nl]);
  }
}

// pack b_w (1024x8) and mix_w (1024x8) transposed into wqkvT rows 3072..3087
__global__ __launch_bounds__(256) void k_pack_bg(const float* __restrict__ b_w, const float* __restrict__ mix_w,
                                                 u16* __restrict__ dst) {
  int idx = blockIdx.x * 256 + threadIdx.x;  // 0..16383
  int r = idx >> 10, d = idx & 1023;
  float v = r < 8 ? b_w[d * 8 + r] : mix_w[d * 8 + (r - 8)];
  dst[(size_t)r * 1024 + d] = f2bf(v);
}

// ---------------------------------------------------------------------------
// bf16 GEMM: C[M,N] = A[M,K] * Bt[N,K]^T ; 128x128 tile, 4 waves, 16x16x32 MFMA
// XCD-chunked block swizzle (requires grid count % 8 == 0)
// ---------------------------------------------------------------------------
template<bool STORE_BF16>
__global__ __launch_bounds__(256) void gemm_bt(const u16* __restrict__ A, const u16* __restrict__ Bt,
                                               void* __restrict__ Cout, int M, int N, int K) {
  __shared__ u16 Ash[128 * 32];
  __shared__ u16 Bsh[128 * 32];
  const int tid = threadIdx.x;
  const int lane = tid & 63, w = tid >> 6;
  const int wr = w >> 1, wc = w & 1;
  const int g = lane >> 4, li = lane & 15;
  const int nbx = gridDim.x * gridDim.y;
  const int bid = blockIdx.y * gridDim.x + blockIdx.x;
  const int wg = (bid & 7) * (nbx >> 3) + (bid >> 3);
  const int mblk = (wg / gridDim.x) * 128, nblk = (wg % gridDim.x) * 128;
  const int srow = tid >> 2, sslot = tid & 3;

  f32x4 acc[4][4];
#pragma unroll
  for (int m = 0; m < 4; ++m)
#pragma unroll
    for (int n = 0; n < 4; ++n) acc[m][n] = (f32x4){0.f, 0.f, 0.f, 0.f};

  for (int kt = 0; kt < K; kt += 32) {
    __syncthreads();
#pragma unroll
    for (int half = 0; half < 2; ++half) {
      int row = srow + half * 64;
      int gk = kt + ((sslot ^ (row & 3)) << 3);  // XOR-swizzled source k-group
      gl_lds16(A + (size_t)(mblk + row) * K + gk, (char*)Ash + tid * 16 + half * 4096);
      gl_lds16(Bt + (size_t)(nblk + row) * K + gk, (char*)Bsh + tid * 16 + half * 4096);
    }
    __syncthreads();
    bf16x8 af[4], bfr[4];
#pragma unroll
    for (int m = 0; m < 4; ++m) {
      int row = wr * 64 + m * 16 + li;
      af[m] = *(const bf16x8*)&Ash[row * 32 + ((g ^ (li & 3)) << 3)];
    }
#pragma unroll
    for (int n = 0; n < 4; ++n) {
      int row = wc * 64 + n * 16 + li;
      bfr[n] = *(const bf16x8*)&Bsh[row * 32 + ((g ^ (li & 3)) << 3)];
    }
#pragma unroll
    for (int m = 0; m < 4; ++m)
#pragma unroll
      for (int n = 0; n < 4; ++n)
        acc[m][n] = __builtin_amdgcn_mfma_f32_16x16x32_bf16(af[m], bfr[n], acc[m][n], 0, 0, 0);
  }
#pragma unroll
  for (int m = 0; m < 4; ++m)
#pragma unroll
    for (int n = 0; n < 4; ++n)
#pragma unroll
      for (int r = 0; r < 4; ++r) {
        int grow = mblk + wr * 64 + m * 16 + g * 4 + r;
        int gcol = nblk + wc * 64 + n * 16 + li;
        if constexpr (STORE_BF16)
          ((u16*)Cout)[(size_t)grow * N + gcol] = f2bf(acc[m][n][r]);
        else
          ((float*)Cout)[(size_t)grow * N + gcol] = acc[m][n][r];
      }
}

// ---------------------------------------------------------------------------
// causal depthwise conv(K=4) + SiLU + per-head l2norm(q,k) + beta scaling.
// Reads fused qkv [8192][3200]; beta/mix logits at cols 3072..3087.
// ---------------------------------------------------------------------------
__global__ __launch_bounds__(256) void k_conv(const u16* __restrict__ qkv,
                                              const float* __restrict__ cqw, const float* __restrict__ ckw,
                                              const float* __restrict__ cvw,
                                              const float* __restrict__ mix_b, const float* __restrict__ mix_bias,
                                              u16* __restrict__ qn, u16* __restrict__ kn, u16* __restrict__ kb,
                                              u16* __restrict__ vb, u16* __restrict__ vtok,
                                              float* __restrict__ gg) {
  const int t = blockIdx.x;
  const int l = t & (L_ - 1);
  const int b = t >> 12;
  const int tid = threadIdx.x;
  const int c = tid * 4;
  const int h = c >> 7, dk = c & 127;
  float aq[4] = {0, 0, 0, 0}, ak[4] = {0, 0, 0, 0}, av[4] = {0, 0, 0, 0};
#pragma unroll
  for (int i = 0; i < 4; ++i) {
    int lr = l - 3 + i;
    if (lr < 0) continue;
    size_t off = (size_t)(t - 3 + i) * QKV_N + c;
    u16x4 xq = *(const u16x4*)(qkv + off);
    u16x4 xk = *(const u16x4*)(qkv + off + 1024);
    u16x4 xv = *(const u16x4*)(qkv + off + 2048);
#pragma unroll
    for (int j = 0; j < 4; ++j) {
      aq[j] += bf2f(xq[j]) * cqw[(c + j) * 4 + i];
      ak[j] += bf2f(xk[j]) * ckw[(c + j) * 4 + i];
      av[j] += bf2f(xv[j]) * cvw[(c + j) * 4 + i];
    }
  }
#pragma unroll
  for (int j = 0; j < 4; ++j) {
    aq[j] = aq[j] / (1.f + expf(-aq[j]));
    ak[j] = ak[j] / (1.f + expf(-ak[j]));
    av[j] = av[j] / (1.f + expf(-av[j]));
  }
  float sq = aq[0] * aq[0] + aq[1] * aq[1] + aq[2] * aq[2] + aq[3] * aq[3];
  float sk = ak[0] * ak[0] + ak[1] * ak[1] + ak[2] * ak[2] + ak[3] * ak[3];
#pragma unroll
  for (int m = 1; m <= 16; m <<= 1) {
    sq += __shfl_xor(sq, m);
    sk += __shfl_xor(sk, m);
  }
  float rq = rsqrtf(sq + 1e-12f), rk = rsqrtf(sk + 1e-12f);
  float bv = 1.f / (1.f + expf(-bf2f(qkv[(size_t)t * QKV_N + 3072 + h])));
  if (dk == 0) {
    float gz = bf2f(qkv[(size_t)t * QKV_N + 3080 + h]) + mix_b[h] + mix_bias[h];
    gg[t * 8 + h] = 1.f / (1.f + expf(-gz));
  }
  size_t hoff = ((size_t)(b * 8 + h) * L_ + l) * 128 + dk;
  u16x4 oq, ok, okb, ovb, ovt;
#pragma unroll
  for (int j = 0; j < 4; ++j) {
    float kq = aq[j] * rq;
    float kk = ak[j] * rk;
    oq[j] = f2bf(kq);
    ok[j] = f2bf(kk);
    okb[j] = f2bf(kk * bv);
    ovb[j] = f2bf(av[j] * bv);
    ovt[j] = f2bf(av[j]);
  }
  *(u16x4*)(qn + hoff) = oq;
  *(u16x4*)(kn + hoff) = ok;
  *(u16x4*)(kb + hoff) = okb;
  *(u16x4*)(vb + hoff) = ovb;
  *(u16x4*)(vtok + (size_t)t * 1024 + c) = ovt;
}

// ---------------------------------------------------------------------------
// per-(bh,chunk): X = (I + strict_tril(kb@kn^T))^-1 ; u=X@vb ; w=X@kb ;
// attn = tril(qn@kn^T). Outputs packed in MFMA-fragment blob for the scan.
// LDS tiles use stride 136 (b128-aligned, bank-spread for row-parallel reads).
// ---------------------------------------------------------------------------
__global__ __launch_bounds__(256) void k_chunkprep(const u16* __restrict__ qn, const u16* __restrict__ kn,
                                                   const u16* __restrict__ kb, const u16* __restrict__ vb,
                                                   u16* __restrict__ blob) {
  const int blk = blockIdx.x;  // bh*NC + chunk
  const int bh = blk >> 7, ch = blk & 127;
  const int tid = threadIdx.x;
  __shared__ u16 kbl[32 * 136], knl[32 * 136], vbl[32 * 136], qnl[32 * 136];
  __shared__ float Af[32][33];
  __shared__ float X[32][33];
  __shared__ u16 w_s[4096], u_s[4096], attn_s[1024];
  size_t base = ((size_t)bh * L_ + (size_t)ch * 32) * 128;
#pragma unroll
  for (int rep = 0; rep < 2; ++rep) {
    int lin = rep * 2048 + tid * 8;
    int row = lin >> 7, col = lin & 127;
    *(u16x8*)&kbl[row * 136 + col] = *(const u16x8*)(kb + base + lin);
    *(u16x8*)&knl[row * 136 + col] = *(const u16x8*)(kn + base + lin);
    *(u16x8*)&vbl[row * 136 + col] = *(const u16x8*)(vb + base + lin);
    *(u16x8*)&qnl[row * 136 + col] = *(const u16x8*)(qn + base + lin);
  }
  __syncthreads();
  {
    const int i = tid >> 3;
    const int j0 = (tid & 7) * 4;
    float a[4] = {0, 0, 0, 0};
    float q[4] = {0, 0, 0, 0};
    for (int d8 = 0; d8 < 16; ++d8) {
      u16x8 kbv = *(const u16x8*)&kbl[i * 136 + d8 * 8];
      u16x8 qnv = *(const u16x8*)&qnl[i * 136 + d8 * 8];
#pragma unroll
      for (int jj = 0; jj < 4; ++jj) {
        u16x8 knv = *(const u16x8*)&knl[(j0 + jj) * 136 + d8 * 8];
#pragma unroll
        for (int e = 0; e < 8; ++e) {
          a[jj] += bf2f(kbv[e]) * bf2f(knv[e]);
          q[jj] += bf2f(qnv[e]) * bf2f(knv[e]);
        }
      }
    }
#pragma unroll
    for (int jj = 0; jj < 4; ++jj) {
      Af[i][j0 + jj] = a[jj];
      attn_s[i * 32 + j0 + jj] = f2bf((j0 + jj) <= i ? q[jj] : 0.f);
    }
  }
  __syncthreads();
  if (tid < 32) {
    int j = tid;  // column j of X, fully lane-local
    for (int i = 0; i < 32; ++i) X[i][j] = (i == j) ? 1.f : 0.f;
    for (int i = j + 1; i < 32; ++i) {
      float s = 0.f;
      for (int m = j; m < i; ++m) s += Af[i][m] * X[m][j];
      X[i][j] = -s;
    }
  }
  __syncthreads();
  {
    const int i = tid >> 3;
    const int d0 = (tid & 7) * 16;
    float ua[16], wa[16];
#pragma unroll
    for (int dd = 0; dd < 16; ++dd) { ua[dd] = 0.f; wa[dd] = 0.f; }
    for (int m = 0; m <= i; ++m) {
      float xv = X[i][m];
      u16x8 v0 = *(const u16x8*)&vbl[m * 136 + d0];
      u16x8 v1 = *(const u16x8*)&vbl[m * 136 + d0 + 8];
      u16x8 k0 = *(const u16x8*)&kbl[m * 136 + d0];
      u16x8 k1 = *(const u16x8*)&kbl[m * 136 + d0 + 8];
#pragma unroll
      for (int e = 0; e < 8; ++e) {
        ua[e] += xv * bf2f(v0[e]);
        ua[8 + e] += xv * bf2f(v1[e]);
        wa[e] += xv * bf2f(k0[e]);
        wa[8 + e] += xv * bf2f(k1[e]);
      }
    }
#pragma unroll
    for (int part = 0; part < 2; ++part) {
      u16x8 su, sw;
#pragma unroll
      for (int e = 0; e < 8; ++e) {
        su[e] = f2bf(ua[part * 8 + e]);
        sw[e] = f2bf(wa[part * 8 + e]);
      }
      *(u16x8*)&u_s[i * 128 + d0 + part * 8] = su;
      *(u16x8*)&w_s[i * 128 + d0 + part * 8] = sw;
    }
  }
  __syncthreads();
  // ---- blob assembly (fragment order; 16B vector writes, coalesced) ----
  u16* bp = blob + (size_t)blk * BLOB_ELEMS;
#pragma unroll
  for (int it = 0; it < 2; ++it) {
    const int v8 = tid * 2 + it;  // 0..511
    const int f = v8 >> 6, l = v8 & 63;
    const int li = l & 15, g = l >> 4;
    {  // w and q A-fragments
      int mw = f >> 2, ks = f & 3;
      int row = mw * 16 + li, c0 = ks * 32 + g * 8;
      *(u16x8*)(bp + WOFF + (size_t)v8 * 8) = *(const u16x8*)&w_s[row * 128 + c0];
      *(u16x8*)(bp + QOFF + (size_t)v8 * 8) = *(const u16x8*)&qnl[row * 136 + c0];
    }
    {  // kt A-fragments: kt[dk][c] = kn[c][dk]
      int dk = f * 16 + li, c0 = g * 8;
      u16x8 tv;
#pragma unroll
      for (int e = 0; e < 8; ++e) tv[e] = knl[(c0 + e) * 136 + dk];
      *(u16x8*)(bp + KTOFF + (size_t)v8 * 8) = tv;
    }
    {  // u^T fragments: ((sg*2+mw)*64 + l)*4 + r  = u[mw*16+g*4+r][sg*16+li]
      int smw = v8 >> 5, l0 = (v8 * 2) & 63;
      int s_ = smw >> 1, mw = smw & 1;
      u16x8 tv;
#pragma unroll
      for (int half = 0; half < 2; ++half) {
        int ll = l0 + half, lli = ll & 15, lg = ll >> 4;
#pragma unroll
        for (int r = 0; r < 4; ++r)
          tv[half * 4 + r] = u_s[(mw * 16 + lg * 4 + r) * 128 + s_ * 16 + lli];
      }
      *(u16x8*)(bp + UTOFF + (size_t)v8 * 8) = tv;
    }
  }
  if (tid < 128) {  // attn A-fragments
    const int v8 = tid;
    const int mw = v8 >> 6, l = v8 & 63;
    const int li = l & 15, g = l >> 4;
    *(u16x8*)(bp + AOFF + (size_t)v8 * 8) = *(const u16x8*)&attn_s[(mw * 16 + li) * 32 + g * 8];
  }
}

// ---------------------------------------------------------------------------
// sequential inter-chunk scan; block = (bh, dv-half); 4 waves = 4 slices of 16.
// Per-chunk operand blob double-buffered in LDS via global_load_lds prefetch.
// ---------------------------------------------------------------------------
DEV void stage_blob(const u16* g, u16* l, int tid) {
#pragma unroll
  for (int it = 0; it < 8; ++it) {
    int off = it * 4096 + tid * 16;
    gl_lds16((const char*)g + off, (char*)l + off);
  }
  if (tid < 128) {
    int off = 32768 + tid * 16;
    gl_lds16((const char*)g + off, (char*)l + off);
  }
}

__global__ __launch_bounds__(256) void k_scan(const u16* __restrict__ blob, u16* __restrict__ o_out) {
  __shared__ u16 lds[2 * BLOB_ELEMS + 4 * 2176 + 4 * 640];  // 90 KiB -> 1 block/CU
  const int blk = blockIdx.x;  // 0..31
  const int bh = blk >> 1, b2 = blk & 1;
  const int b = bh >> 3, h = bh & 7;
  const int tid = threadIdx.x;
  const int s = tid >> 6, lane = tid & 63;
  const int g = lane >> 4, li = lane & 15;
  const int sg = b2 * 4 + s;   // global dv-slice 0..7
  const int c0 = sg * 16;
  u16* buf0 = lds;
  u16* buf1 = lds + BLOB_ELEMS;
  u16* st = lds + 2 * BLOB_ELEMS + s * 2176;             // per-wave S_t [16][136]
  u16* uft = lds + 2 * BLOB_ELEMS + 4 * 2176 + s * 640;  // per-wave uf_t [16][40]

  f32x4 S[8];
#pragma unroll
  for (int mi = 0; mi < 8; ++mi) S[mi] = (f32x4){0.f, 0.f, 0.f, 0.f};

  const u16* gb = blob + (size_t)bh * NC * BLOB_ELEMS;
  stage_blob(gb, buf0, tid);
  __syncthreads();

  for (int ch = 0; ch < NC; ++ch) {
    const u16* bp = (ch & 1) ? buf1 : buf0;
    if (ch + 1 < NC) stage_blob(gb + (size_t)(ch + 1) * BLOB_ELEMS, (ch & 1) ? buf0 : buf1, tid);

    // export S (f32 acc, C-layout) -> bf16 transposed, read back as B-frags
#pragma unroll
    for (int mi = 0; mi < 8; ++mi) {
      u16x4 sv;
#pragma unroll
      for (int r = 0; r < 4; ++r) sv[r] = f2bf(S[mi][r]);
      *(u16x4*)&st[li * 136 + mi * 16 + g * 4] = sv;
    }
    bf16x8 bS[4];
#pragma unroll
    for (int ks = 0; ks < 4; ++ks)
      bS[ks] = *(const bf16x8*)&st[li * 136 + ks * 32 + g * 8];

    // t1 = w_i @ S
    f32x4 t1[2];
    t1[0] = (f32x4){0.f, 0.f, 0.f, 0.f};
    t1[1] = (f32x4){0.f, 0.f, 0.f, 0.f};
#pragma unroll
    for (int mw = 0; mw < 2; ++mw)
#pragma unroll
      for (int ks = 0; ks < 4; ++ks) {
        bf16x8 aw = *(const bf16x8*)&bp[WOFF + ((size_t)((mw * 4 + ks) * 64 + lane)) * 8];
        t1[mw] = __builtin_amdgcn_mfma_f32_16x16x32_bf16(aw, bS[ks], t1[mw], 0, 0, 0);
      }
    // ufix = u_i - t1 -> per-wave transposed LDS -> B-frag
#pragma unroll
    for (int mw = 0; mw < 2; ++mw) {
      u16x4 uv = *(const u16x4*)&bp[UTOFF + ((size_t)((sg * 2 + mw) * 64 + lane)) * 4];
      u16x4 ufv;
#pragma unroll
      for (int r = 0; r < 4; ++r) ufv[r] = f2bf(bf2f(uv[r]) - t1[mw][r]);
      *(u16x4*)&uft[li * 40 + mw * 16 + g * 4] = ufv;
    }
    bf16x8 bUF = *(const bf16x8*)&uft[li * 40 + g * 8];

    // o = q_i @ S + attn_i @ ufix
    f32x4 oa[2];
    oa[0] = (f32x4){0.f, 0.f, 0.f, 0.f};
    oa[1] = (f32x4){0.f, 0.f, 0.f, 0.f};
#pragma unroll
    for (int mw = 0; mw < 2; ++mw)
#pragma unroll
      for (int ks = 0; ks < 4; ++ks) {
        bf16x8 aq = *(const bf16x8*)&bp[QOFF + ((size_t)((mw * 4 + ks) * 64 + lane)) * 8];
        oa[mw] = __builtin_amdgcn_mfma_f32_16x16x32_bf16(aq, bS[ks], oa[mw], 0, 0, 0);
      }
#pragma unroll
    for (int mw = 0; mw < 2; ++mw) {
      bf16x8 aat = *(const bf16x8*)&bp[AOFF + ((size_t)(mw * 64 + lane)) * 8];
      oa[mw] = __builtin_amdgcn_mfma_f32_16x16x32_bf16(aat, bUF, oa[mw], 0, 0, 0);
    }
    // write o (token-major)
    size_t obase = ((size_t)b * L_ + ch * 32 + g * 4) * 1024 + h * 128 + c0 + li;
#pragma unroll
    for (int mw = 0; mw < 2; ++mw)
#pragma unroll
      for (int r = 0; r < 4; ++r)
        o_out[obase + (size_t)(mw * 16 + r) * 1024] = f2bf(oa[mw][r]);
    // S += k_i^T @ ufix
#pragma unroll
    for (int mi = 0; mi < 8; ++mi) {
      bf16x8 akt = *(const bf16x8*)&bp[KTOFF + ((size_t)(mi * 64 + lane)) * 8];
      S[mi] = __builtin_amdgcn_mfma_f32_16x16x32_bf16(akt, bUF, S[mi], 0, 0, 0);
    }
    __syncthreads();  // prefetch landed (vmcnt0) + all waves done with bp
  }
}

// ---------------------------------------------------------------------------
// o = g*o + (1-g)*v_token ; RMS over DV ; * o_norm_w ; -> bf16 for final GEMM
// ---------------------------------------------------------------------------
__global__ __launch_bounds__(256) void k_mixnorm(const u16* __restrict__ o_mid, const u16* __restrict__ vtok,
                                                 const float* __restrict__ g, const float* __restrict__ onw,
                                                 u16* __restrict__ omix) {
  int t = blockIdx.x, tid = threadIdx.x;
  int c = tid * 4, h = c >> 7, dk = c & 127;
  float gv = g[t * 8 + h];
  u16x4 ov = *(const u16x4*)(o_mid + (size_t)t * 1024 + c);
  u16x4 vv = *(const u16x4*)(vtok + (size_t)t * 1024 + c);
  float mx[4];
#pragma unroll
  for (int j = 0; j < 4; ++j) mx[j] = gv * bf2f(ov[j]) + (1.f - gv) * bf2f(vv[j]);
  float ss = mx[0] * mx[0] + mx[1] * mx[1] + mx[2] * mx[2] + mx[3] * mx[3];
#pragma unroll
  for (int m = 1; m <= 16; m <<= 1) ss += __shfl_xor(ss, m);
  float r = rsqrtf(ss * (1.f / 128.f) + 1e-5f);
  u16x4 oo;
#pragma unroll
  for (int j = 0; j < 4; ++j) oo[j] = f2bf(mx[j] * r * onw[dk + j]);
  *(u16x4*)(omix + (size_t)t * 1024 + c) = oo;
}

// ---------------------------------------------------------------------------
extern "C" void kernel_launch(void* const* d_in, const int* in_sizes, int n_in,
                              void* d_out, int out_size, void* d_ws, size_t ws_size,
                              hipStream_t stream) {
  const float* hidden = (const float*)d_in[0];
  const float* q_w = (const float*)d_in[1];
  const float* k_w = (const float*)d_in[2];
  const float* v_w = (const float*)d_in[3];
  const float* cqw = (const float*)d_in[4];
  const float* ckw = (const float*)d_in[5];
  const float* cvw = (const float*)d_in[6];
  const float* b_w = (const float*)d_in[7];
  const float* mix_w = (const float*)d_in[8];
  const float* mix_b = (const float*)d_in[9];
  const float* mix_bias = (const float*)d_in[10];
  const float* onw = (const float*)d_in[11];
  const float* o_w = (const float*)d_in[12];

  char* ws = (char*)d_ws;
  size_t off = 0;
  auto alloc = [&](size_t bytes) {
    char* p = ws + off;
    off += (bytes + 255) & ~(size_t)255;
    return p;
  };
  u16* hbf = (u16*)alloc(16777216);      // hidden bf16; reused as omix at the end
  u16* wqkvT = (u16*)alloc((size_t)QKV_N * 1024 * 2);  // [3200][1024]
  u16* woT = (u16*)alloc(2097152);
  float* gg = (float*)alloc(262144);
  u16* qn = (u16*)alloc(16777216);       // reused as scan output o after chunkprep
  u16* kn = (u16*)alloc(16777216);
  u16* kbn = (u16*)alloc(16777216);
  u16* vbn = (u16*)alloc(16777216);
  u16* vtok = (u16*)alloc(16777216);
  u16* blob = (u16*)alloc(71303168);     // 16 bh * 128 ch * 34816 B (fragment blob)
  if (off > ws_size) return;

  // fused qkv GEMM output [8192][3200] aliases the (not-yet-written) blob
  u16* qkv = blob;
  u16* obuf = qn;  // scan output aliases qn (dead after chunkprep)

  k_f32_to_bf16<<<8192, 256, 0, stream>>>(hidden, hbf, 2097152);
  k_transpose_w<<<dim3(32, 32, 4), 256, 0, stream>>>(q_w, k_w, v_w, o_w,
                                                     wqkvT, wqkvT + 1024 * 1024,
                                                     wqkvT + 2 * 1024 * 1024, woT);
  k_pack_bg<<<64, 256, 0, stream>>>(b_w, mix_w, wqkvT + (size_t)3072 * 1024);
  gemm_bt<true><<<dim3(25, 64), 256, 0, stream>>>(hbf, wqkvT, qkv, BL, QKV_N, 1024);
  k_conv<<<8192, 256, 0, stream>>>(qkv, cqw, ckw, cvw, mix_b, mix_bias,
                                   qn, kn, kbn, vbn, vtok, gg);
  k_chunkprep<<<2048, 256, 0, stream>>>(qn, kn, kbn, vbn, blob);
  k_scan<<<32, 256, 0, stream>>>(blob, obuf);
  k_mixnorm<<<8192, 256, 0, stream>>>(obuf, vtok, gg, onw, hbf);
  gemm_bt<false><<<dim3(8, 64), 256, 0, stream>>>(hbf, woT, d_out, BL, 1024, 1024);
}

// Round 4
// 478.509 us; speedup vs baseline: 2.3441x; 1.2608x over previous
//
#include <hip/hip_runtime.h>
#include <cstdint>
#include <cstddef>

typedef unsigned short u16;
typedef unsigned int u32;
typedef __attribute__((ext_vector_type(4))) u16 u16x4;
typedef __attribute__((ext_vector_type(8))) u16 u16x8;
typedef __attribute__((ext_vector_type(4))) float f32x4;
typedef __attribute__((ext_vector_type(8))) __bf16 bf16x8;

#define DEV static __device__ __forceinline__

DEV u16 f2bf(float f) {  // HW RTNE convert
  __bf16 h = (__bf16)f;
  return __builtin_bit_cast(u16, h);
}
DEV float bf2f(u16 s) { return __builtin_bit_cast(float, (u32)s << 16); }
DEV float sigm(float x) { return __builtin_amdgcn_rcpf(1.f + __expf(-x)); }

DEV void gl_lds16(const void* g, void* l) {
  __builtin_amdgcn_global_load_lds((const __attribute__((address_space(1))) u32*)g,
                                   (__attribute__((address_space(3))) u32*)l, 16, 0, 0);
}

constexpr int B_ = 2, L_ = 4096, H_ = 8;
constexpr int BL = B_ * L_;   // 8192 tokens
constexpr int NC = L_ / 32;   // 128 chunks per sequence
constexpr int QKV_N = 3200;   // 3*1024 qkv + 16 beta/mix logit cols + 112 pad

// blob layout per (bh,chunk), u16 element offsets; total 17408 elems = 34816 B
constexpr int WOFF = 0;       // w   A-frags: ((mw*4+ks)*64 + lane)*8 + e
constexpr int QOFF = 4096;    // q   A-frags: same mapping
constexpr int KTOFF = 8192;   // k^T A-frags: (mi*64 + lane)*8 + e
constexpr int AOFF = 12288;   // attn A-frags: (mw*64 + lane)*8 + e
constexpr int UTOFF = 13312;  // u^T  frags: ((sg*2+mw)*64 + lane)*4 + r
constexpr int BLOB_ELEMS = 17408;

// ---------------------------------------------------------------------------
__global__ __launch_bounds__(256) void k_f32_to_bf16(const float* __restrict__ src,
                                                     u16* __restrict__ dst, int n4) {
  int i = blockIdx.x * 256 + threadIdx.x;
  if (i < n4) {
    f32x4 v = *(const f32x4*)(src + (size_t)i * 4);
    u16x4 o;
#pragma unroll
    for (int j = 0; j < 4; ++j) o[j] = f2bf(v[j]);
    *(u16x4*)(dst + (size_t)i * 4) = o;
  }
}

// ---------------------------------------------------------------------------
// transpose 1024x1024 f32 weights -> bf16 [n][k]; q,k,v go into one [3200][1024]
// ---------------------------------------------------------------------------
__global__ __launch_bounds__(256) void k_transpose_w(const float* __restrict__ s0, const float* __restrict__ s1,
                                                     const float* __restrict__ s2, const float* __restrict__ s3,
                                                     u16* __restrict__ d0, u16* __restrict__ d1,
                                                     u16* __restrict__ d2, u16* __restrict__ d3) {
  const float* src = blockIdx.z == 0 ? s0 : blockIdx.z == 1 ? s1 : blockIdx.z == 2 ? s2 : s3;
  u16* dst = blockIdx.z == 0 ? d0 : blockIdx.z == 1 ? d1 : blockIdx.z == 2 ? d2 : d3;
  __shared__ float tile[32][33];
  int k0 = blockIdx.y * 32, n0 = blockIdx.x * 32;
  int ty = threadIdx.x >> 5, tx = threadIdx.x & 31;
#pragma unroll
  for (int i = 0; i < 4; ++i)
    tile[ty + 8 * i][tx] = src[(size_t)(k0 + ty + 8 * i) * 1024 + n0 + tx];
  __syncthreads();
#pragma unroll
  for (int i = 0; i < 4; ++i) {
    int nl = ty + 8 * i;
    dst[(size_t)(n0 + nl) * 1024 + k0 + tx] = f2bf(tile[tx][nl]);
  }
}

// pack b_w (1024x8) and mix_w (1024x8) transposed into wqkvT rows 3072..3087
__global__ __launch_bounds__(256) void k_pack_bg(const float* __restrict__ b_w, const float* __restrict__ mix_w,
                                                 u16* __restrict__ dst) {
  int idx = blockIdx.x * 256 + threadIdx.x;  // 0..16383
  int r = idx >> 10, d = idx & 1023;
  float v = r < 8 ? b_w[d * 8 + r] : mix_w[d * 8 + (r - 8)];
  dst[(size_t)r * 1024 + d] = f2bf(v);
}

// ---------------------------------------------------------------------------
// bf16 GEMM: C[M,N] = A[M,K] * Bt[N,K]^T ; 128x128 tile, 4 waves, 16x16x32 MFMA
// XCD-chunked block swizzle (requires grid count % 8 == 0)
// ---------------------------------------------------------------------------
template<bool STORE_BF16>
__global__ __launch_bounds__(256) void gemm_bt(const u16* __restrict__ A, const u16* __restrict__ Bt,
                                               void* __restrict__ Cout, int M, int N, int K) {
  __shared__ u16 Ash[128 * 32];
  __shared__ u16 Bsh[128 * 32];
  const int tid = threadIdx.x;
  const int lane = tid & 63, w = tid >> 6;
  const int wr = w >> 1, wc = w & 1;
  const int g = lane >> 4, li = lane & 15;
  const int nbx = gridDim.x * gridDim.y;
  const int bid = blockIdx.y * gridDim.x + blockIdx.x;
  const int wg = (bid & 7) * (nbx >> 3) + (bid >> 3);
  const int mblk = (wg / gridDim.x) * 128, nblk = (wg % gridDim.x) * 128;
  const int srow = tid >> 2, sslot = tid & 3;

  f32x4 acc[4][4];
#pragma unroll
  for (int m = 0; m < 4; ++m)
#pragma unroll
    for (int n = 0; n < 4; ++n) acc[m][n] = (f32x4){0.f, 0.f, 0.f, 0.f};

  for (int kt = 0; kt < K; kt += 32) {
    __syncthreads();
#pragma unroll
    for (int half = 0; half < 2; ++half) {
      int row = srow + half * 64;
      int gk = kt + ((sslot ^ (row & 3)) << 3);  // XOR-swizzled source k-group
      gl_lds16(A + (size_t)(mblk + row) * K + gk, (char*)Ash + tid * 16 + half * 4096);
      gl_lds16(Bt + (size_t)(nblk + row) * K + gk, (char*)Bsh + tid * 16 + half * 4096);
    }
    __syncthreads();
    bf16x8 af[4], bfr[4];
#pragma unroll
    for (int m = 0; m < 4; ++m) {
      int row = wr * 64 + m * 16 + li;
      af[m] = *(const bf16x8*)&Ash[row * 32 + ((g ^ (li & 3)) << 3)];
    }
#pragma unroll
    for (int n = 0; n < 4; ++n) {
      int row = wc * 64 + n * 16 + li;
      bfr[n] = *(const bf16x8*)&Bsh[row * 32 + ((g ^ (li & 3)) << 3)];
    }
#pragma unroll
    for (int m = 0; m < 4; ++m)
#pragma unroll
      for (int n = 0; n < 4; ++n)
        acc[m][n] = __builtin_amdgcn_mfma_f32_16x16x32_bf16(af[m], bfr[n], acc[m][n], 0, 0, 0);
  }
#pragma unroll
  for (int m = 0; m < 4; ++m)
#pragma unroll
    for (int n = 0; n < 4; ++n)
#pragma unroll
      for (int r = 0; r < 4; ++r) {
        int grow = mblk + wr * 64 + m * 16 + g * 4 + r;
        int gcol = nblk + wc * 64 + n * 16 + li;
        if constexpr (STORE_BF16)
          ((u16*)Cout)[(size_t)grow * N + gcol] = f2bf(acc[m][n][r]);
        else
          ((float*)Cout)[(size_t)grow * N + gcol] = acc[m][n][r];
      }
}

// ---------------------------------------------------------------------------
// causal depthwise conv(K=4) + SiLU + per-head l2norm(q,k) + beta scaling.
// Token-tiled: block = (bh, 32-token tile); q/k/v head-slices staged in LDS.
// ---------------------------------------------------------------------------
__global__ __launch_bounds__(256) void k_conv(const u16* __restrict__ qkv,
                                              const float* __restrict__ cqw, const float* __restrict__ ckw,
                                              const float* __restrict__ cvw,
                                              const float* __restrict__ mix_b, const float* __restrict__ mix_bias,
                                              u16* __restrict__ qn, u16* __restrict__ kn, u16* __restrict__ kb,
                                              u16* __restrict__ vb, u16* __restrict__ vtok,
                                              float* __restrict__ gg) {
  const int blk = blockIdx.x;          // bh*128 + tile
  const int bh = blk >> 7, tile = blk & 127;
  const int b = bh >> 3, h = bh & 7;
  const int t0 = tile * 32;
  const int tid = threadIdx.x;
  __shared__ u16 lq[35 * 136], lk[35 * 136], lv[35 * 136];
  __shared__ float bval[32];

  // ---- stage 35 token-rows x 128 ch x 3 streams into LDS (zero left pad) ----
#pragma unroll
  for (int it = 0; it < 7; ++it) {
    int li = it * 256 + tid;
    if (li >= 1680) break;              // 3 streams * 35 rows * 16 chunks
    int strm = li / 560;
    int rem = li - strm * 560;
    int row = rem >> 4, e8 = rem & 15;
    int l = t0 - 3 + row;
    u16* dst = strm == 0 ? lq : strm == 1 ? lk : lv;
    u16x8 val = (u16x8){0, 0, 0, 0, 0, 0, 0, 0};
    if (l >= 0)
      val = *(const u16x8*)(qkv + (size_t)(b * L_ + l) * QKV_N + strm * 1024 + h * 128 + e8 * 8);
    *(u16x8*)&dst[row * 136 + e8 * 8] = val;
  }
  if (tid < 32) {  // beta + g logits for this tile's 32 tokens
    int gt = b * L_ + t0 + tid;
    bval[tid] = sigm(bf2f(qkv[(size_t)gt * QKV_N + 3072 + h]));
    float gz = bf2f(qkv[(size_t)gt * QKV_N + 3080 + h]) + mix_b[h] + mix_bias[h];
    gg[gt * 8 + h] = sigm(gz);
  }
  __syncthreads();

  // ---- each thread: one token x 16 channels ----
  const int tok = tid >> 3, cg = tid & 7;
  const int l = t0 + tok;
  float aq[16], ak[16], av[16];

  auto do_stream = [&](const u16* lbuf, const float* wbase, float* acc) {
    u16x8 r0[4], r1[4];
#pragma unroll
    for (int i = 0; i < 4; ++i) {
      int base = (tok + i) * 136 + cg * 16;
      r0[i] = *(const u16x8*)&lbuf[base];
      r1[i] = *(const u16x8*)&lbuf[base + 8];
    }
#pragma unroll
    for (int e = 0; e < 8; ++e) {
      f32x4 w0 = *(const f32x4*)(wbase + e * 4);
      f32x4 w1 = *(const f32x4*)(wbase + (e + 8) * 4);
      float s0 = 0.f, s1 = 0.f;
#pragma unroll
      for (int i = 0; i < 4; ++i) {
        s0 += bf2f(r0[i][e]) * w0[i];
        s1 += bf2f(r1[i][e]) * w1[i];
      }
      acc[e] = s0;
      acc[e + 8] = s1;
    }
  };
  const int chb = (h * 128 + cg * 16) * 4;
  do_stream(lq, cqw + chb, aq);
  do_stream(lk, ckw + chb, ak);
  do_stream(lv, cvw + chb, av);

  float sq2 = 0.f, sk2 = 0.f;
#pragma unroll
  for (int e = 0; e < 16; ++e) {
    aq[e] = aq[e] * sigm(aq[e]);
    ak[e] = ak[e] * sigm(ak[e]);
    av[e] = av[e] * sigm(av[e]);
    sq2 += aq[e] * aq[e];
    sk2 += ak[e] * ak[e];
  }
#pragma unroll
  for (int m = 1; m <= 4; m <<= 1) {
    sq2 += __shfl_xor(sq2, m);
    sk2 += __shfl_xor(sk2, m);
  }
  float rq = rsqrtf(sq2 + 1e-12f), rk = rsqrtf(sk2 + 1e-12f);
  float bv = bval[tok];
  size_t hoff = ((size_t)bh * L_ + l) * 128 + cg * 16;
  size_t toff = ((size_t)(b * L_ + l)) * 1024 + h * 128 + cg * 16;
#pragma unroll
  for (int part = 0; part < 2; ++part) {
    u16x8 oq, ok, okb, ovb, ovt;
#pragma unroll
    for (int e = 0; e < 8; ++e) {
      float q = aq[part * 8 + e] * rq;
      float kk = ak[part * 8 + e] * rk;
      float vv = av[part * 8 + e];
      oq[e] = f2bf(q);
      ok[e] = f2bf(kk);
      okb[e] = f2bf(kk * bv);
      ovb[e] = f2bf(vv * bv);
      ovt[e] = f2bf(vv);
    }
    *(u16x8*)(qn + hoff + part * 8) = oq;
    *(u16x8*)(kn + hoff + part * 8) = ok;
    *(u16x8*)(kb + hoff + part * 8) = okb;
    *(u16x8*)(vb + hoff + part * 8) = ovb;
    *(u16x8*)(vtok + toff + part * 8) = ovt;
  }
}

// ---------------------------------------------------------------------------
// per-(bh,chunk): X = (I + strict_tril(kb@kn^T))^-1 ; u=X@vb ; w=X@kb ;
// attn = tril(qn@kn^T). Outputs packed in MFMA-fragment blob for the scan.
// ---------------------------------------------------------------------------
__global__ __launch_bounds__(256) void k_chunkprep(const u16* __restrict__ qn, const u16* __restrict__ kn,
                                                   const u16* __restrict__ kb, const u16* __restrict__ vb,
                                                   u16* __restrict__ blob) {
  const int blk = blockIdx.x;  // bh*NC + chunk
  const int bh = blk >> 7, ch = blk & 127;
  const int tid = threadIdx.x;
  __shared__ u16 kbl[32 * 136], knl[32 * 136], vbl[32 * 136], qnl[32 * 136];
  __shared__ float Af[32][33];
  __shared__ float X[32][33];
  __shared__ u16 w_s[4096], u_s[4096], attn_s[1024];
  size_t base = ((size_t)bh * L_ + (size_t)ch * 32) * 128;
#pragma unroll
  for (int rep = 0; rep < 2; ++rep) {
    int lin = rep * 2048 + tid * 8;
    int row = lin >> 7, col = lin & 127;
    *(u16x8*)&kbl[row * 136 + col] = *(const u16x8*)(kb + base + lin);
    *(u16x8*)&knl[row * 136 + col] = *(const u16x8*)(kn + base + lin);
    *(u16x8*)&vbl[row * 136 + col] = *(const u16x8*)(vb + base + lin);
    *(u16x8*)&qnl[row * 136 + col] = *(const u16x8*)(qn + base + lin);
  }
  __syncthreads();
  {
    const int i = tid >> 3;
    const int j0 = (tid & 7) * 4;
    float a[4] = {0, 0, 0, 0};
    float q[4] = {0, 0, 0, 0};
    for (int d8 = 0; d8 < 16; ++d8) {
      u16x8 kbv = *(const u16x8*)&kbl[i * 136 + d8 * 8];
      u16x8 qnv = *(const u16x8*)&qnl[i * 136 + d8 * 8];
#pragma unroll
      for (int jj = 0; jj < 4; ++jj) {
        u16x8 knv = *(const u16x8*)&knl[(j0 + jj) * 136 + d8 * 8];
#pragma unroll
        for (int e = 0; e < 8; ++e) {
          a[jj] += bf2f(kbv[e]) * bf2f(knv[e]);
          q[jj] += bf2f(qnv[e]) * bf2f(knv[e]);
        }
      }
    }
#pragma unroll
    for (int jj = 0; jj < 4; ++jj) {
      Af[i][j0 + jj] = a[jj];
      attn_s[i * 32 + j0 + jj] = f2bf((j0 + jj) <= i ? q[jj] : 0.f);
    }
  }
  __syncthreads();
  if (tid < 32) {
    int j = tid;  // column j of X, fully lane-local
    for (int i = 0; i < 32; ++i) X[i][j] = (i == j) ? 1.f : 0.f;
    for (int i = j + 1; i < 32; ++i) {
      float s = 0.f;
      for (int m = j; m < i; ++m) s += Af[i][m] * X[m][j];
      X[i][j] = -s;
    }
  }
  __syncthreads();
  {
    const int i = tid >> 3;
    const int d0 = (tid & 7) * 16;
    float ua[16], wa[16];
#pragma unroll
    for (int dd = 0; dd < 16; ++dd) { ua[dd] = 0.f; wa[dd] = 0.f; }
    for (int m = 0; m <= i; ++m) {
      float xv = X[i][m];
      u16x8 v0 = *(const u16x8*)&vbl[m * 136 + d0];
      u16x8 v1 = *(const u16x8*)&vbl[m * 136 + d0 + 8];
      u16x8 k0 = *(const u16x8*)&kbl[m * 136 + d0];
      u16x8 k1 = *(const u16x8*)&kbl[m * 136 + d0 + 8];
#pragma unroll
      for (int e = 0; e < 8; ++e) {
        ua[e] += xv * bf2f(v0[e]);
        ua[8 + e] += xv * bf2f(v1[e]);
        wa[e] += xv * bf2f(k0[e]);
        wa[8 + e] += xv * bf2f(k1[e]);
      }
    }
#pragma unroll
    for (int part = 0; part < 2; ++part) {
      u16x8 su, sw;
#pragma unroll
      for (int e = 0; e < 8; ++e) {
        su[e] = f2bf(ua[part * 8 + e]);
        sw[e] = f2bf(wa[part * 8 + e]);
      }
      *(u16x8*)&u_s[i * 128 + d0 + part * 8] = su;
      *(u16x8*)&w_s[i * 128 + d0 + part * 8] = sw;
    }
  }
  __syncthreads();
  // ---- blob assembly (fragment order; 16B vector writes, coalesced) ----
  u16* bp = blob + (size_t)blk * BLOB_ELEMS;
#pragma unroll
  for (int it = 0; it < 2; ++it) {
    const int v8 = tid * 2 + it;  // 0..511
    const int f = v8 >> 6, l = v8 & 63;
    const int li = l & 15, g = l >> 4;
    {  // w and q A-fragments
      int mw = f >> 2, ks = f & 3;
      int row = mw * 16 + li, c0 = ks * 32 + g * 8;
      *(u16x8*)(bp + WOFF + (size_t)v8 * 8) = *(const u16x8*)&w_s[row * 128 + c0];
      *(u16x8*)(bp + QOFF + (size_t)v8 * 8) = *(const u16x8*)&qnl[row * 136 + c0];
    }
    {  // kt A-fragments: kt[dk][c] = kn[c][dk]
      int dk = f * 16 + li, c0 = g * 8;
      u16x8 tv;
#pragma unroll
      for (int e = 0; e < 8; ++e) tv[e] = knl[(c0 + e) * 136 + dk];
      *(u16x8*)(bp + KTOFF + (size_t)v8 * 8) = tv;
    }
    {  // u^T fragments: ((sg*2+mw)*64 + l)*4 + r  = u[mw*16+g*4+r][sg*16+li]
      int smw = v8 >> 5, l0 = (v8 * 2) & 63;
      int s_ = smw >> 1, mw = smw & 1;
      u16x8 tv;
#pragma unroll
      for (int half = 0; half < 2; ++half) {
        int ll = l0 + half, lli = ll & 15, lg = ll >> 4;
#pragma unroll
        for (int r = 0; r < 4; ++r)
          tv[half * 4 + r] = u_s[(mw * 16 + lg * 4 + r) * 128 + s_ * 16 + lli];
      }
      *(u16x8*)(bp + UTOFF + (size_t)v8 * 8) = tv;
    }
  }
  if (tid < 128) {  // attn A-fragments
    const int v8 = tid;
    const int mw = v8 >> 6, l = v8 & 63;
    const int li = l & 15, g = l >> 4;
    *(u16x8*)(bp + AOFF + (size_t)v8 * 8) = *(const u16x8*)&attn_s[(mw * 16 + li) * 32 + g * 8];
  }
}

// ---------------------------------------------------------------------------
// sequential inter-chunk scan; block = (bh, dv-half); 4 waves = 4 slices of 16.
// Per-chunk operand blob double-buffered in LDS via global_load_lds prefetch.
// ---------------------------------------------------------------------------
DEV void stage_blob(const u16* g, u16* l, int tid) {
#pragma unroll
  for (int it = 0; it < 8; ++it) {
    int off = it * 4096 + tid * 16;
    gl_lds16((const char*)g + off, (char*)l + off);
  }
  if (tid < 128) {
    int off = 32768 + tid * 16;
    gl_lds16((const char*)g + off, (char*)l + off);
  }
}

__global__ __launch_bounds__(256) void k_scan(const u16* __restrict__ blob, u16* __restrict__ o_out) {
  __shared__ u16 lds[2 * BLOB_ELEMS + 4 * 2176 + 4 * 640];  // 90 KiB -> 1 block/CU
  const int blk = blockIdx.x;  // 0..31
  const int bh = blk >> 1, b2 = blk & 1;
  const int b = bh >> 3, h = bh & 7;
  const int tid = threadIdx.x;
  const int s = tid >> 6, lane = tid & 63;
  const int g = lane >> 4, li = lane & 15;
  const int sg = b2 * 4 + s;   // global dv-slice 0..7
  const int c0 = sg * 16;
  u16* buf0 = lds;
  u16* buf1 = lds + BLOB_ELEMS;
  u16* st = lds + 2 * BLOB_ELEMS + s * 2176;             // per-wave S_t [16][136]
  u16* uft = lds + 2 * BLOB_ELEMS + 4 * 2176 + s * 640;  // per-wave uf_t [16][40]

  f32x4 S[8];
#pragma unroll
  for (int mi = 0; mi < 8; ++mi) S[mi] = (f32x4){0.f, 0.f, 0.f, 0.f};

  const u16* gb = blob + (size_t)bh * NC * BLOB_ELEMS;
  stage_blob(gb, buf0, tid);
  __syncthreads();

  for (int ch = 0; ch < NC; ++ch) {
    const u16* bp = (ch & 1) ? buf1 : buf0;
    if (ch + 1 < NC) stage_blob(gb + (size_t)(ch + 1) * BLOB_ELEMS, (ch & 1) ? buf0 : buf1, tid);

    // export S (f32 acc, C-layout) -> bf16 transposed, read back as B-frags
#pragma unroll
    for (int mi = 0; mi < 8; ++mi) {
      u16x4 sv;
#pragma unroll
      for (int r = 0; r < 4; ++r) sv[r] = f2bf(S[mi][r]);
      *(u16x4*)&st[li * 136 + mi * 16 + g * 4] = sv;
    }
    bf16x8 bS[4];
#pragma unroll
    for (int ks = 0; ks < 4; ++ks)
      bS[ks] = *(const bf16x8*)&st[li * 136 + ks * 32 + g * 8];

    // t1 = w_i @ S
    f32x4 t1[2];
    t1[0] = (f32x4){0.f, 0.f, 0.f, 0.f};
    t1[1] = (f32x4){0.f, 0.f, 0.f, 0.f};
#pragma unroll
    for (int mw = 0; mw < 2; ++mw)
#pragma unroll
      for (int ks = 0; ks < 4; ++ks) {
        bf16x8 aw = *(const bf16x8*)&bp[WOFF + ((size_t)((mw * 4 + ks) * 64 + lane)) * 8];
        t1[mw] = __builtin_amdgcn_mfma_f32_16x16x32_bf16(aw, bS[ks], t1[mw], 0, 0, 0);
      }
    // ufix = u_i - t1 -> per-wave transposed LDS -> B-frag
#pragma unroll
    for (int mw = 0; mw < 2; ++mw) {
      u16x4 uv = *(const u16x4*)&bp[UTOFF + ((size_t)((sg * 2 + mw) * 64 + lane)) * 4];
      u16x4 ufv;
#pragma unroll
      for (int r = 0; r < 4; ++r) ufv[r] = f2bf(bf2f(uv[r]) - t1[mw][r]);
      *(u16x4*)&uft[li * 40 + mw * 16 + g * 4] = ufv;
    }
    bf16x8 bUF = *(const bf16x8*)&uft[li * 40 + g * 8];

    // o = q_i @ S + attn_i @ ufix
    f32x4 oa[2];
    oa[0] = (f32x4){0.f, 0.f, 0.f, 0.f};
    oa[1] = (f32x4){0.f, 0.f, 0.f, 0.f};
#pragma unroll
    for (int mw = 0; mw < 2; ++mw)
#pragma unroll
      for (int ks = 0; ks < 4; ++ks) {
        bf16x8 aq = *(const bf16x8*)&bp[QOFF + ((size_t)((mw * 4 + ks) * 64 + lane)) * 8];
        oa[mw] = __builtin_amdgcn_mfma_f32_16x16x32_bf16(aq, bS[ks], oa[mw], 0, 0, 0);
      }
#pragma unroll
    for (int mw = 0; mw < 2; ++mw) {
      bf16x8 aat = *(const bf16x8*)&bp[AOFF + ((size_t)(mw * 64 + lane)) * 8];
      oa[mw] = __builtin_amdgcn_mfma_f32_16x16x32_bf16(aat, bUF, oa[mw], 0, 0, 0);
    }
    // write o (token-major)
    size_t obase = ((size_t)b * L_ + ch * 32 + g * 4) * 1024 + h * 128 + c0 + li;
#pragma unroll
    for (int mw = 0; mw < 2; ++mw)
#pragma unroll
      for (int r = 0; r < 4; ++r)
        o_out[obase + (size_t)(mw * 16 + r) * 1024] = f2bf(oa[mw][r]);
    // S += k_i^T @ ufix
#pragma unroll
    for (int mi = 0; mi < 8; ++mi) {
      bf16x8 akt = *(const bf16x8*)&bp[KTOFF + ((size_t)(mi * 64 + lane)) * 8];
      S[mi] = __builtin_amdgcn_mfma_f32_16x16x32_bf16(akt, bUF, S[mi], 0, 0, 0);
    }
    __syncthreads();  // prefetch landed (vmcnt0) + all waves done with bp
  }
}

// ---------------------------------------------------------------------------
// o = g*o + (1-g)*v_token ; RMS over DV ; * o_norm_w ; -> bf16 for final GEMM
// ---------------------------------------------------------------------------
__global__ __launch_bounds__(256) void k_mixnorm(const u16* __restrict__ o_mid, const u16* __restrict__ vtok,
                                                 const float* __restrict__ g, const float* __restrict__ onw,
                                                 u16* __restrict__ omix) {
  int t = blockIdx.x, tid = threadIdx.x;
  int c = tid * 4, h = c >> 7, dk = c & 127;
  float gv = g[t * 8 + h];
  u16x4 ov = *(const u16x4*)(o_mid + (size_t)t * 1024 + c);
  u16x4 vv = *(const u16x4*)(vtok + (size_t)t * 1024 + c);
  float mx[4];
#pragma unroll
  for (int j = 0; j < 4; ++j) mx[j] = gv * bf2f(ov[j]) + (1.f - gv) * bf2f(vv[j]);
  float ss = mx[0] * mx[0] + mx[1] * mx[1] + mx[2] * mx[2] + mx[3] * mx[3];
#pragma unroll
  for (int m = 1; m <= 16; m <<= 1) ss += __shfl_xor(ss, m);
  float r = rsqrtf(ss * (1.f / 128.f) + 1e-5f);
  u16x4 oo;
#pragma unroll
  for (int j = 0; j < 4; ++j) oo[j] = f2bf(mx[j] * r * onw[dk + j]);
  *(u16x4*)(omix + (size_t)t * 1024 + c) = oo;
}

// ---------------------------------------------------------------------------
extern "C" void kernel_launch(void* const* d_in, const int* in_sizes, int n_in,
                              void* d_out, int out_size, void* d_ws, size_t ws_size,
                              hipStream_t stream) {
  const float* hidden = (const float*)d_in[0];
  const float* q_w = (const float*)d_in[1];
  const float* k_w = (const float*)d_in[2];
  const float* v_w = (const float*)d_in[3];
  const float* cqw = (const float*)d_in[4];
  const float* ckw = (const float*)d_in[5];
  const float* cvw = (const float*)d_in[6];
  const float* b_w = (const float*)d_in[7];
  const float* mix_w = (const float*)d_in[8];
  const float* mix_b = (const float*)d_in[9];
  const float* mix_bias = (const float*)d_in[10];
  const float* onw = (const float*)d_in[11];
  const float* o_w = (const float*)d_in[12];

  char* ws = (char*)d_ws;
  size_t off = 0;
  auto alloc = [&](size_t bytes) {
    char* p = ws + off;
    off += (bytes + 255) & ~(size_t)255;
    return p;
  };
  u16* hbf = (u16*)alloc(16777216);      // hidden bf16; reused as omix at the end
  u16* wqkvT = (u16*)alloc((size_t)QKV_N * 1024 * 2);  // [3200][1024]
  u16* woT = (u16*)alloc(2097152);
  float* gg = (float*)alloc(262144);
  u16* qn = (u16*)alloc(16777216);       // reused as scan output o after chunkprep
  u16* kn = (u16*)alloc(16777216);
  u16* kbn = (u16*)alloc(16777216);
  u16* vbn = (u16*)alloc(16777216);
  u16* vtok = (u16*)alloc(16777216);
  u16* blob = (u16*)alloc(71303168);     // 16 bh * 128 ch * 34816 B (fragment blob)
  if (off > ws_size) return;

  // fused qkv GEMM output [8192][3200] aliases the (not-yet-written) blob
  u16* qkv = blob;
  u16* obuf = qn;  // scan output aliases qn (dead after chunkprep)

  k_f32_to_bf16<<<8192, 256, 0, stream>>>(hidden, hbf, 2097152);
  k_transpose_w<<<dim3(32, 32, 4), 256, 0, stream>>>(q_w, k_w, v_w, o_w,
                                                     wqkvT, wqkvT + 1024 * 1024,
                                                     wqkvT + 2 * 1024 * 1024, woT);
  k_pack_bg<<<64, 256, 0, stream>>>(b_w, mix_w, wqkvT + (size_t)3072 * 1024);
  gemm_bt<true><<<dim3(25, 64), 256, 0, stream>>>(hbf, wqkvT, qkv, BL, QKV_N, 1024);
  k_conv<<<2048, 256, 0, stream>>>(qkv, cqw, ckw, cvw, mix_b, mix_bias,
                                   qn, kn, kbn, vbn, vtok, gg);
  k_chunkprep<<<2048, 256, 0, stream>>>(qn, kn, kbn, vbn, blob);
  k_scan<<<32, 256, 0, stream>>>(blob, obuf);
  k_mixnorm<<<8192, 256, 0, stream>>>(obuf, vtok, gg, onw, hbf);
  gemm_bt<false><<<dim3(8, 64), 256, 0, stream>>>(hbf, woT, d_out, BL, 1024, 1024);
}